// Round 14
// baseline (184.375 us; speedup 1.0000x reference)
//
#include <hip/hip_runtime.h>
#include <math.h>

#define BATCH   8
#define SEQ     4096
#define DMODEL  256
#define DINNER  512
#define DSTATE  64
#define NHEADS  8
#define HEADDIM 64
#define CONVDIM 640          // DINNER + 2*DSTATE
#define DPROJ   1160         // full in-proj rows (for W_in/dt indexing)
#define ZSTR    1152         // z | xBC columns actually materialized (9*128)
#define NROWS   (BATCH*SEQ)  // 32768
#define CHUNK   64
#define NCHUNK  (SEQ/CHUNK)  // 64
#define LSTR    72           // LDS row stride for chunk_state (shorts)

typedef short bf16x8 __attribute__((ext_vector_type(8)));
typedef short short8v __attribute__((ext_vector_type(8)));
typedef float f32x4 __attribute__((ext_vector_type(4)));

// ---- static workspace (BSS) ----
__device__ short g_xn[(size_t)NROWS * DMODEL];      // bf16 16.8 MB
__device__ short g_zxb[(size_t)NROWS * ZSTR];       // bf16 75.5 MB (z | xBC)
__device__ short g_xbc[(size_t)NROWS * CONVDIM];    // bf16 42.0 MB (conv out; x-slice overwritten by gated v)
__device__ float g_dt[(size_t)NROWS * NHEADS];      // fp32  1.0 MB (raw dt, pre-bias)
__device__ float g_rowss[(size_t)NROWS * NHEADS];   // fp32  1.0 MB (per-row per-head sum of v^2)
__device__ short g_lstate[(size_t)BATCH * NHEADS * NCHUNK * HEADDIM * DSTATE]; // bf16 33.5 MB
__device__ float g_decayC[BATCH * NHEADS * NCHUNK];
__device__ short g_Winb[(size_t)ZSTR * DMODEL];     // bf16 W_in rows 0..1151
__device__ short g_Woutb[(size_t)DMODEL * DINNER];  // bf16 W_out * gnorm_w

__device__ __forceinline__ short f2bf(float f) {
    unsigned u = __float_as_uint(f);
    u += 0x7fff + ((u >> 16) & 1);
    return (short)(u >> 16);
}
__device__ __forceinline__ float bf2f(short s) {
    return __uint_as_float(((unsigned)(unsigned short)s) << 16);
}

__device__ __forceinline__ void stage16(const void* gsrc, void* ldst) {
    __builtin_amdgcn_global_load_lds(
        (const __attribute__((address_space(1))) void*)gsrc,
        (__attribute__((address_space(3))) void*)ldst, 16, 0, 0);
}

// element offset in a [64][64] bf16 tile with XOR chunk swizzle
__device__ __forceinline__ int swz(int row, int col) {
    return row * 64 + ((((col >> 3) ^ row) & 7) << 3) + (col & 7);
}

// ---------------- weight convert: fp32 -> bf16 ----------------
__global__ __launch_bounds__(256) void convert_bf16_kernel(const float* __restrict__ src,
                                                           short* __restrict__ dst,
                                                           int n_valid, int n_total) {
    const int i = blockIdx.x * 256 + threadIdx.x;
    if (i < n_total) dst[i] = (i < n_valid) ? f2bf(src[i]) : (short)0;
}

// ---------------- W_out convert with gnorm_w folded ----------------
__global__ __launch_bounds__(256) void convert_wout_kernel(const float* __restrict__ src,
                                                           const float* __restrict__ gw,
                                                           short* __restrict__ dst) {
    const int i = blockIdx.x * 256 + threadIdx.x;
    if (i < DMODEL * DINNER) dst[i] = f2bf(src[i] * gw[i % DINNER]);
}

// ---------------- rmsnorm of x (D=256) -> bf16 xn AND exact fp32 dt (8 heads) ----------
__global__ __launch_bounds__(256) void rmsnorm_dt_kernel(const float* __restrict__ x,
                                                         const float* __restrict__ w,
                                                         const float* __restrict__ W_in,
                                                         short* __restrict__ xn,
                                                         float* __restrict__ dt) {
    const int row  = blockIdx.x * 4 + (threadIdx.x >> 6);
    const int lane = threadIdx.x & 63;
    const float4 v = *(const float4*)(x + (size_t)row * DMODEL + lane * 4);
    float ss = v.x * v.x + v.y * v.y + v.z * v.z + v.w * v.w;
#pragma unroll
    for (int off = 1; off < 64; off <<= 1) ss += __shfl_xor(ss, off);
    const float rs = rsqrtf(ss * (1.0f / DMODEL) + 1.1920929e-7f);
    const float4 wv = *(const float4*)(w + lane * 4);
    const float4 xn4 = make_float4(v.x * rs * wv.x, v.y * rs * wv.y,
                                   v.z * rs * wv.z, v.w * rs * wv.w);
    short4 o;
    o.x = f2bf(xn4.x); o.y = f2bf(xn4.y); o.z = f2bf(xn4.z); o.w = f2bf(xn4.w);
    *(short4*)(xn + (size_t)row * DMODEL + lane * 4) = o;
#pragma unroll
    for (int h = 0; h < NHEADS; ++h) {
        const float4 ww = *(const float4*)(W_in + (size_t)(DPROJ - NHEADS + h) * DMODEL + lane * 4);
        float p = xn4.x * ww.x + xn4.y * ww.y + xn4.z * ww.z + xn4.w * ww.w;
#pragma unroll
        for (int off = 1; off < 64; off <<= 1) p += __shfl_xor(p, off);
        if (lane == 0) dt[(size_t)row * NHEADS + h] = p;
    }
}

// ---------------- bf16 MFMA GEMM: C[M][N] = A[M][K] * B[N][K]^T ----------
template <bool RES, typename OUT>
__global__ __launch_bounds__(256) void gemm_bf16_nt(const short* __restrict__ A,
                                                    const short* __restrict__ B,
                                                    const float* __restrict__ R,
                                                    const float* __restrict__ RS,
                                                    OUT* __restrict__ C,
                                                    int NX, int M, int N, int K, int LDA) {
    const int L   = blockIdx.x;
    const int xcd = L & 7;
    const int r   = L >> 3;
    const int mstrips_per_xcd = (M / 128) >> 3;
    const int mblk = xcd * mstrips_per_xcd + r / NX;
    const int nblk = r % NX;
    const int m0 = mblk * 128, n0 = nblk * 128;

    __shared__ __align__(16) short Asl[128 * 64];   // 16 KB
    __shared__ __align__(16) short Bsl[128 * 64];   // 16 KB
    const int tid  = threadIdx.x;
    const int lane = tid & 63;
    const int wid  = tid >> 6;
    const int wrow = (wid >> 1) * 64, wcol = (wid & 1) * 64;

    f32x4 acc[4][4];
#pragma unroll
    for (int m = 0; m < 4; ++m)
#pragma unroll
        for (int n = 0; n < 4; ++n) acc[m][n] = (f32x4)0.f;

    const int wbase = (tid & 0xC0) * 8;

    for (int k0 = 0; k0 < K; k0 += 64) {
#pragma unroll
        for (int rr = 0; rr < 4; ++rr) {
            const int idx = rr * 256 + tid;
            const int row = idx >> 3;
            const int cs  = idx & 7;
            const int ko  = (cs ^ (row & 7)) * 8;
            const int r6  = row & 63;
            const int brow = (row & 64) + (((r6 & 15) << 2) | (r6 >> 4));
            stage16(A + (size_t)(m0 + row) * LDA + k0 + ko, Asl + rr * 2048 + wbase);
            stage16(B + (size_t)(n0 + brow) * K + k0 + ko, Bsl + rr * 2048 + wbase);
        }
        __syncthreads();
#pragma unroll
        for (int ks = 0; ks < 2; ++ks) {
            bf16x8 af[4], bfr[4];
#pragma unroll
            for (int m = 0; m < 4; ++m) {
                const int arow = wrow + m * 16 + (lane & 15);
                const int ch = (ks * 4 + (lane >> 4)) ^ (arow & 7);
                af[m] = *(const bf16x8*)(Asl + arow * 64 + ch * 8);
            }
#pragma unroll
            for (int n = 0; n < 4; ++n) {
                const int brw = wcol + n * 16 + (lane & 15);
                const int ch = (ks * 4 + (lane >> 4)) ^ (brw & 7);
                bfr[n] = *(const bf16x8*)(Bsl + brw * 64 + ch * 8);
            }
#pragma unroll
            for (int m = 0; m < 4; ++m)
#pragma unroll
                for (int n = 0; n < 4; ++n)
                    acc[m][n] = __builtin_amdgcn_mfma_f32_16x16x32_bf16(af[m], bfr[n], acc[m][n], 0, 0, 0);
        }
        __syncthreads();
    }

    const int r0 = (lane >> 4) * 4;
    const int gcol = n0 + wcol + (lane & 15) * 4;
#pragma unroll
    for (int m = 0; m < 4; ++m) {
        const int grow = m0 + wrow + m * 16 + r0;
        if (gcol < N) {
#pragma unroll
            for (int reg = 0; reg < 4; ++reg) {
                if constexpr (sizeof(OUT) == 2) {
                    short4 o;
                    o.x = f2bf(acc[m][0][reg]); o.y = f2bf(acc[m][1][reg]);
                    o.z = f2bf(acc[m][2][reg]); o.w = f2bf(acc[m][3][reg]);
                    *(short4*)(C + (size_t)(grow + reg) * N + gcol) = o;
                } else {
                    f32x4 v;
                    v[0] = acc[m][0][reg]; v[1] = acc[m][1][reg];
                    v[2] = acc[m][2][reg]; v[3] = acc[m][3][reg];
                    if (RES) {
                        const float* rp = RS + (size_t)(grow + reg) * NHEADS;
                        const f32x4 s0 = *(const f32x4*)rp;
                        const f32x4 s1 = *(const f32x4*)(rp + 4);
                        const float sum = s0[0] + s0[1] + s0[2] + s0[3] +
                                          s1[0] + s1[1] + s1[2] + s1[3];
                        const float rsn = rsqrtf(sum * (1.0f / DINNER) + 1e-5f);
                        v *= rsn;
                        v += *(const f32x4*)(R + (size_t)(grow + reg) * N + gcol);
                    }
                    *(f32x4*)(C + (size_t)(grow + reg) * N + gcol) = v;
                }
            }
        }
    }
}

// ---- depthwise causal conv(4) + bias + SiLU: sliding window, 8 rows x 8 ch per thread ----
__global__ __launch_bounds__(256) void conv_silu_kernel(const short* __restrict__ zxb,
                                                        const float* __restrict__ cw,
                                                        const float* __restrict__ cb,
                                                        short* __restrict__ xbc) {
    const int idx = blockIdx.x * 256 + threadIdx.x;   // over (NROWS/8)*80
    const int c8  = (idx % 80) * 8;
    const int bl0 = (idx / 80) * 8;                   // first of 8 rows
    const int l0  = bl0 & (SEQ - 1);
    const short* src = zxb + (size_t)bl0 * ZSTR + DINNER + c8;

    float4 w4[8];
    float bias[8];
#pragma unroll
    for (int j = 0; j < 8; ++j) w4[j] = *(const float4*)(cw + (c8 + j) * 4);
    {
        const float4 b0 = *(const float4*)(cb + c8);
        const float4 b1 = *(const float4*)(cb + c8 + 4);
        bias[0] = b0.x; bias[1] = b0.y; bias[2] = b0.z; bias[3] = b0.w;
        bias[4] = b1.x; bias[5] = b1.y; bias[6] = b1.z; bias[7] = b1.w;
    }

    bf16x8 rowv[11];                                  // rows l0-3 .. l0+7
#pragma unroll
    for (int m = 0; m < 11; ++m) {
        if (l0 + m - 3 >= 0)
            rowv[m] = *(const bf16x8*)(src + (ptrdiff_t)(m - 3) * ZSTR);
        else
            rowv[m] = (bf16x8)0;
    }

#pragma unroll
    for (int r = 0; r < 8; ++r) {
        float acc[8];
#pragma unroll
        for (int j = 0; j < 8; ++j) acc[j] = bias[j];
#pragma unroll
        for (int k = 0; k < 4; ++k) {
            const bf16x8 tap = rowv[r + k];
#pragma unroll
            for (int j = 0; j < 8; ++j)
                acc[j] = fmaf(bf2f(tap[j]), ((const float*)&w4[j])[k], acc[j]);
        }
        short8v o;
#pragma unroll
        for (int j = 0; j < 8; ++j) {
            const float s = acc[j];
            o[j] = f2bf(s / (1.f + __expf(-s)));
        }
        *(short8v*)(xbc + (size_t)(bl0 + r) * CONVDIM + c8) = o;
    }
}

// ---------------- scan pass 1 (MFMA): L[p][n] = sum_t X[t][p] * (w_t * B[t][n]) ----------
__global__ __launch_bounds__(256) void chunk_state_mfma(const float* __restrict__ dt,
                                                        const short* __restrict__ xbc,
                                                        const float* __restrict__ dt_bias,
                                                        const float* __restrict__ A_log,
                                                        short* __restrict__ lstate,
                                                        float* __restrict__ decayC) {
    const int bhc = blockIdx.x;
    const int c = bhc & (NCHUNK - 1), bh = bhc >> 6, h = bh & (NHEADS - 1), b = bh >> 3;
    const int tid = threadIdx.x, lane = tid & 63, wid = tid >> 6;
    __shared__ short XT[64 * LSTR];   // X^T, slot-permuted
    __shared__ short BT[64 * LSTR];   // (w*B)^T, slot-permuted
    __shared__ float wsh[CHUNK];
    const size_t row0 = (size_t)b * SEQ + (size_t)c * CHUNK;

    const float aneg  = -__expf(A_log[h]);
    const float dbias = dt_bias[h];
    if (tid < 64) {
        const float draw = dt[(row0 + tid) * NHEADS + h] + dbias;
        const float dtv  = (draw > 20.f) ? draw : log1pf(__expf(draw));
        float cum = aneg * dtv;
#pragma unroll
        for (int off = 1; off < 64; off <<= 1) {
            const float nv = __shfl_up(cum, off);
            if (lane >= off) cum += nv;
        }
        const float total = __shfl(cum, 63);
        wsh[tid] = __expf(total - cum) * dtv;
        if (tid == 63) decayC[bhc] = __expf(cum);
    }
    __syncthreads();

#pragma unroll
    for (int r = 0; r < 4; ++r) {
        const int idx  = tid + r * 256;
        const int trow = idx >> 4;
        const int q    = idx & 15;
        const int c4   = q * 4;
        const short* rp = xbc + (row0 + trow) * CONVDIM;
        const short4 xv = *(const short4*)(rp + h * 64 + c4);
        const short4 bv = *(const short4*)(rp + DINNER + c4);
        const float w = wsh[trow];
        XT[(0 * 16 + q) * LSTR + trow] = xv.x;
        XT[(1 * 16 + q) * LSTR + trow] = xv.y;
        XT[(2 * 16 + q) * LSTR + trow] = xv.z;
        XT[(3 * 16 + q) * LSTR + trow] = xv.w;
        BT[(0 * 16 + q) * LSTR + trow] = f2bf(bf2f(bv.x) * w);
        BT[(1 * 16 + q) * LSTR + trow] = f2bf(bf2f(bv.y) * w);
        BT[(2 * 16 + q) * LSTR + trow] = f2bf(bf2f(bv.z) * w);
        BT[(3 * 16 + q) * LSTR + trow] = f2bf(bf2f(bv.w) * w);
    }
    __syncthreads();

    f32x4 acc[4];
#pragma unroll
    for (int n = 0; n < 4; ++n) acc[n] = (f32x4)0.f;
#pragma unroll
    for (int ks = 0; ks < 2; ++ks) {
        const bf16x8 af = *(const bf16x8*)(XT + (wid * 16 + (lane & 15)) * LSTR + ks * 32 + (lane >> 4) * 8);
#pragma unroll
        for (int n = 0; n < 4; ++n) {
            const bf16x8 bfv = *(const bf16x8*)(BT + (n * 16 + (lane & 15)) * LSTR + ks * 32 + (lane >> 4) * 8);
            acc[n] = __builtin_amdgcn_mfma_f32_16x16x32_bf16(af, bfv, acc[n], 0, 0, 0);
        }
    }
    short* lp = lstate + ((size_t)bhc << 12);
    const int hi = lane >> 4;
    const int ncol = (lane & 15) * 4;
#pragma unroll
    for (int reg = 0; reg < 4; ++reg) {
        const int p = 16 * hi + 4 * reg + wid;
        short4 o;
        o.x = f2bf(acc[0][reg]); o.y = f2bf(acc[1][reg]);
        o.z = f2bf(acc[2][reg]); o.w = f2bf(acc[3][reg]);
        *(short4*)(lp + p * 64 + ncol) = o;
    }
}

// ---------------- scan pass 2: inter-chunk recurrence, short4-wide ----------
__global__ __launch_bounds__(256) void state_prefix_kernel(short* __restrict__ lstate,
                                                           const float* __restrict__ decayC) {
    const int idx = blockIdx.x * 256 + threadIdx.x;
    const int bh  = idx >> 10;
    const int pn4 = (idx & 1023) * 4;
    float S0 = 0.f, S1 = 0.f, S2 = 0.f, S3 = 0.f;
    for (int c = 0; c < NCHUNK; ++c) {
        short4* ptr = (short4*)(lstate + (((size_t)bh * NCHUNK + c) << 12) + pn4);
        const short4 l4 = *ptr;
        short4 o;
        o.x = f2bf(S0); o.y = f2bf(S1); o.z = f2bf(S2); o.w = f2bf(S3);
        *ptr = o;
        const float d = decayC[bh * NCHUNK + c];
        S0 = fmaf(S0, d, bf2f(l4.x));
        S1 = fmaf(S1, d, bf2f(l4.y));
        S2 = fmaf(S2, d, bf2f(l4.z));
        S3 = fmaf(S3, d, bf2f(l4.w));
    }
}

// ---- scan pass 3 (MFMA), 4 HEADS PER BLOCK: B/C staged once, G=C@B^T computed once
// into registers; per head: mask->Ms (overlays Bs), Y MFMAs, fused gating epilogue.
// Grid = BATCH * 2 * NCHUNK. LDS 32 KB (Bs/Ms, Cs, XT, SP). ----
__global__ __launch_bounds__(256) void chunk_scan_mfma(const float* __restrict__ dt,
                                                       short* __restrict__ xbc,
                                                       const short* __restrict__ zxb,
                                                       float* __restrict__ rowss,
                                                       const float* __restrict__ dt_bias,
                                                       const float* __restrict__ A_log,
                                                       const float* __restrict__ Dp,
                                                       const short* __restrict__ lstate) {
    const int bid = blockIdx.x;
    const int c   = bid & (NCHUNK - 1);
    const int rest = bid >> 6;
    const int hg  = rest & 1;            // head group: heads 4*hg .. 4*hg+3
    const int b   = rest >> 1;
    const int tid = threadIdx.x, lane = tid & 63, wid = tid >> 6;
    __shared__ short BsMs[64 * 64];      // B rows [t][n]; per-head masked scores [s][t]
    __shared__ short Cs[64 * 64];        // C rows [s][n] (persistent)
    __shared__ short XT[64 * 64];        // X^T, slot-permuted (per head)
    __shared__ short SP[64 * 64];        // prefix state, slot-permuted (per head)
    short* Bs = BsMs;
    short* Ms = BsMs;
    const size_t row0 = (size_t)b * SEQ + (size_t)c * CHUNK;

    // ---- stage B, C once ----
#pragma unroll
    for (int r = 0; r < 4; ++r) {
        const int idx  = tid + r * 256;
        const int trow = idx >> 4;
        const int q    = idx & 15;
        const int c4   = q * 4;
        const short* rp = xbc + (row0 + trow) * CONVDIM;
        const int hoff = ((((q >> 1) ^ trow) & 7) << 3) + (q & 1) * 4;
        *(short4*)(Bs + trow * 64 + hoff) = *(const short4*)(rp + DINNER + c4);
        *(short4*)(Cs + trow * 64 + hoff) = *(const short4*)(rp + DINNER + DSTATE + c4);
    }
    __syncthreads();

    // ---- G = C @ B^T once, kept in registers across the head loop ----
    f32x4 accG[4];
#pragma unroll
    for (int tf = 0; tf < 4; ++tf) accG[tf] = (f32x4)0.f;
    __builtin_amdgcn_s_setprio(1);
#pragma unroll
    for (int ks = 0; ks < 2; ++ks) {
        const int crow = wid * 16 + (lane & 15);
        const bf16x8 af = *(const bf16x8*)(Cs + crow * 64 + (((ks * 4 + (lane >> 4)) ^ crow) & 7) * 8);
#pragma unroll
        for (int tf = 0; tf < 4; ++tf) {
            const int brw = tf * 16 + (lane & 15);
            const bf16x8 bfv = *(const bf16x8*)(Bs + brw * 64 + (((ks * 4 + (lane >> 4)) ^ brw) & 7) * 8);
            accG[tf] = __builtin_amdgcn_mfma_f32_16x16x32_bf16(af, bfv, accG[tf], 0, 0, 0);
        }
    }
    __builtin_amdgcn_s_setprio(0);

    const int srow0 = wid * 16 + (lane >> 4) * 4;
    const int j = lane & 15;

    for (int hh = 0; hh < 4; ++hh) {
        const int h = hg * 4 + hh;
        __syncthreads();   // prior iteration done reading Ms/XT/SP (or G-phase done with Bs)

        // ---- stage XT_h (transpose, swizzled) and SP_h ----
#pragma unroll
        for (int r = 0; r < 4; ++r) {
            const int idx  = tid + r * 256;
            const int trow = idx >> 4;
            const int q    = idx & 15;
            const int c4   = q * 4;
            const short4 xv = *(const short4*)(xbc + (row0 + trow) * CONVDIM + h * 64 + c4);
            XT[swz(0 * 16 + q, trow)] = xv.x;
            XT[swz(1 * 16 + q, trow)] = xv.y;
            XT[swz(2 * 16 + q, trow)] = xv.z;
            XT[swz(3 * 16 + q, trow)] = xv.w;
        }
        const size_t lbase = ((size_t)(((b * NHEADS) + h) * NCHUNK + c)) << 12;
#pragma unroll
        for (int r = 0; r < 4; ++r) {
            const int idx = tid + r * 256;
            const int p = idx >> 4, q = idx & 15;
            const int pslot = ((p & 3) << 4) | (p >> 2);
            const int hoff = ((((q >> 1) ^ pslot) & 7) << 3) + (q & 1) * 4;
            *(short4*)(SP + pslot * 64 + hoff) =
                *(const short4*)(lstate + lbase + p * 64 + q * 4);
        }

        // ---- per-head prefix in registers (redundant per wave) ----
        const float aneg = -__expf(A_log[h]);
        const float draw = dt[(row0 + lane) * NHEADS + h] + dt_bias[h];
        const float dtv  = (draw > 20.f) ? draw : log1pf(__expf(draw));
        float cum = aneg * dtv;
#pragma unroll
        for (int off = 1; off < 64; off <<= 1) {
            const float nv = __shfl_up(cum, off);
            if (lane >= off) cum += nv;
        }
        float csr[4];
#pragma unroll
        for (int reg = 0; reg < 4; ++reg) csr[reg] = __shfl(cum, srow0 + reg);

        // ---- mask -> Ms (overlays Bs; writers only, barrier follows) ----
#pragma unroll
        for (int tf = 0; tf < 4; ++tf) {
            const int t = tf * 16 + j;
            const float ct  = __shfl(cum, t);
            const float dtt = __shfl(dtv, t);
#pragma unroll
            for (int reg = 0; reg < 4; ++reg) {
                const int s = srow0 + reg;
                const float m = (t <= s) ? accG[tf][reg] * __expf(csr[reg] - ct) * dtt : 0.f;
                Ms[swz(s, t)] = f2bf(m);
            }
        }
        __syncthreads();

        // ---- Y1 = Ms @ X ; Y2 = C @ SP^T ----
        f32x4 acc1[4], acc2[4];
#pragma unroll
        for (int pf = 0; pf < 4; ++pf) { acc1[pf] = (f32x4)0.f; acc2[pf] = (f32x4)0.f; }
        __builtin_amdgcn_s_setprio(1);
#pragma unroll
        for (int ks = 0; ks < 2; ++ks) {
            const int mrow = wid * 16 + j;
            const int ch = ks * 4 + (lane >> 4);
            const bf16x8 am = *(const bf16x8*)(Ms + mrow * 64 + ((ch ^ mrow) & 7) * 8);
            const bf16x8 ac = *(const bf16x8*)(Cs + mrow * 64 + ((ch ^ mrow) & 7) * 8);
#pragma unroll
            for (int pf = 0; pf < 4; ++pf) {
                const int prow = pf * 16 + j;
                const bf16x8 bx = *(const bf16x8*)(XT + prow * 64 + ((ch ^ prow) & 7) * 8);
                const bf16x8 bs = *(const bf16x8*)(SP + prow * 64 + ((ch ^ prow) & 7) * 8);
                acc1[pf] = __builtin_amdgcn_mfma_f32_16x16x32_bf16(am, bx, acc1[pf], 0, 0, 0);
                acc2[pf] = __builtin_amdgcn_mfma_f32_16x16x32_bf16(ac, bs, acc2[pf], 0, 0, 0);
            }
        }
        __builtin_amdgcn_s_setprio(0);

        // ---- fused gating epilogue ----
        const float dpv = Dp[h];
        float es[4];
#pragma unroll
        for (int reg = 0; reg < 4; ++reg) es[reg] = __expf(csr[reg]);
#pragma unroll
        for (int reg = 0; reg < 4; ++reg) {
            const int s = srow0 + reg;
            const short4 z4 = *(const short4*)(zxb + (row0 + s) * ZSTR + h * 64 + j * 4);
            short4 o;
            float ssq = 0.f;
#pragma unroll
            for (int pf = 0; pf < 4; ++pf) {
                const float xv = bf2f(XT[swz(pf * 16 + j, s)]);
                const float yv = acc1[pf][reg] + es[reg] * acc2[pf][reg] + dpv * xv;
                const float zf = bf2f(((const short*)&z4)[pf]);
                const float v  = yv * zf / (1.f + __expf(-zf));
                ((short*)&o)[pf] = f2bf(v);
                ssq = fmaf(v, v, ssq);
            }
            *(short4*)(xbc + (row0 + s) * CONVDIM + h * 64 + j * 4) = o;
            ssq += __shfl_xor(ssq, 1);
            ssq += __shfl_xor(ssq, 2);
            ssq += __shfl_xor(ssq, 4);
            ssq += __shfl_xor(ssq, 8);
            if (j == 0) rowss[(row0 + s) * NHEADS + h] = ssq;
        }
    }
}

// ---------------- launch ----------------
extern "C" void kernel_launch(void* const* d_in, const int* in_sizes, int n_in,
                              void* d_out, int out_size, void* d_ws, size_t ws_size,
                              hipStream_t stream) {
    (void)in_sizes; (void)n_in; (void)out_size; (void)d_ws; (void)ws_size;
    const float* x      = (const float*)d_in[0];
    const float* W_in   = (const float*)d_in[1];
    const float* conv_w = (const float*)d_in[2];
    const float* conv_b = (const float*)d_in[3];
    const float* dt_b   = (const float*)d_in[4];
    const float* A_log  = (const float*)d_in[5];
    const float* Dp     = (const float*)d_in[6];
    const float* g_w    = (const float*)d_in[7];
    const float* n_w    = (const float*)d_in[8];
    const float* W_out  = (const float*)d_in[9];
    float* out = (float*)d_out;

    short *xn, *zxb, *xbc, *winb, *woutb, *lst;
    float *dtv, *dcy, *rss;
    hipGetSymbolAddress((void**)&xn,    HIP_SYMBOL(g_xn));
    hipGetSymbolAddress((void**)&zxb,   HIP_SYMBOL(g_zxb));
    hipGetSymbolAddress((void**)&xbc,   HIP_SYMBOL(g_xbc));
    hipGetSymbolAddress((void**)&dtv,   HIP_SYMBOL(g_dt));
    hipGetSymbolAddress((void**)&rss,   HIP_SYMBOL(g_rowss));
    hipGetSymbolAddress((void**)&lst,   HIP_SYMBOL(g_lstate));
    hipGetSymbolAddress((void**)&dcy,   HIP_SYMBOL(g_decayC));
    hipGetSymbolAddress((void**)&winb,  HIP_SYMBOL(g_Winb));
    hipGetSymbolAddress((void**)&woutb, HIP_SYMBOL(g_Woutb));

    convert_bf16_kernel<<<(ZSTR * DMODEL) / 256, 256, 0, stream>>>(
        W_in, winb, ZSTR * DMODEL, ZSTR * DMODEL);
    convert_wout_kernel<<<(DMODEL * DINNER) / 256, 256, 0, stream>>>(W_out, g_w, woutb);

    rmsnorm_dt_kernel<<<NROWS / 4, 256, 0, stream>>>(x, n_w, W_in, xn, dtv);

    gemm_bf16_nt<false, short><<<(ZSTR / 128) * (NROWS / 128), 256, 0, stream>>>(
        xn, winb, nullptr, nullptr, zxb, ZSTR / 128, NROWS, ZSTR, DMODEL, DMODEL);

    conv_silu_kernel<<<(NROWS / 8 * 80) / 256, 256, 0, stream>>>(zxb, conv_w, conv_b, xbc);

    chunk_state_mfma<<<BATCH * NHEADS * NCHUNK, 256, 0, stream>>>(dtv, xbc, dt_b, A_log, lst, dcy);
    state_prefix_kernel<<<(BATCH * NHEADS * HEADDIM * DSTATE) / (4 * 256), 256, 0, stream>>>(lst, dcy);
    chunk_scan_mfma<<<BATCH * 2 * NCHUNK, 256, 0, stream>>>(
        dtv, xbc, zxb, rss, dt_b, A_log, Dp, lst);

    gemm_bf16_nt<true, float><<<(DMODEL / 128) * (NROWS / 128), 256, 0, stream>>>(
        xbc, woutb, x, rss, out, DMODEL / 128, NROWS, DMODEL, DINNER, CONVDIM);
}

// Round 15
// 179.077 us; speedup vs baseline: 1.0296x; 1.0296x over previous
//
#include <hip/hip_runtime.h>
#include <math.h>

#define BATCH   8
#define SEQ     4096
#define DMODEL  256
#define DINNER  512
#define DSTATE  64
#define NHEADS  8
#define HEADDIM 64
#define CONVDIM 640          // DINNER + 2*DSTATE
#define DPROJ   1160         // full in-proj rows (for W_in/dt indexing)
#define ZSTR    1152         // z | xBC columns actually materialized (9*128)
#define NROWS   (BATCH*SEQ)  // 32768
#define CHUNK   64
#define NCHUNK  (SEQ/CHUNK)  // 64
#define LSTR    72           // LDS row stride for chunk_state (shorts)

typedef short bf16x8 __attribute__((ext_vector_type(8)));
typedef short short8v __attribute__((ext_vector_type(8)));
typedef float f32x4 __attribute__((ext_vector_type(4)));

// ---- static workspace (BSS) ----
__device__ short g_xn[(size_t)NROWS * DMODEL];      // bf16 16.8 MB
__device__ short g_zxb[(size_t)NROWS * ZSTR];       // bf16 75.5 MB (z | xBC)
__device__ short g_xbc[(size_t)NROWS * CONVDIM];    // bf16 42.0 MB (conv out; x-slice overwritten by gated v)
__device__ float g_dt[(size_t)NROWS * NHEADS];      // fp32  1.0 MB (raw dt, pre-bias)
__device__ float g_rowss[(size_t)NROWS * NHEADS];   // fp32  1.0 MB (per-row per-head sum of v^2)
__device__ short g_lstate[(size_t)BATCH * NHEADS * NCHUNK * HEADDIM * DSTATE]; // bf16 33.5 MB
__device__ float g_decayC[BATCH * NHEADS * NCHUNK];
__device__ short g_Winb[(size_t)ZSTR * DMODEL];     // bf16 W_in rows 0..1151
__device__ short g_Woutb[(size_t)DMODEL * DINNER];  // bf16 W_out * gnorm_w

__device__ __forceinline__ short f2bf(float f) {
    unsigned u = __float_as_uint(f);
    u += 0x7fff + ((u >> 16) & 1);
    return (short)(u >> 16);
}
__device__ __forceinline__ float bf2f(short s) {
    return __uint_as_float(((unsigned)(unsigned short)s) << 16);
}

__device__ __forceinline__ void stage16(const void* gsrc, void* ldst) {
    __builtin_amdgcn_global_load_lds(
        (const __attribute__((address_space(1))) void*)gsrc,
        (__attribute__((address_space(3))) void*)ldst, 16, 0, 0);
}

// element offset in a [64][64] bf16 tile with XOR chunk swizzle
__device__ __forceinline__ int swz(int row, int col) {
    return row * 64 + ((((col >> 3) ^ row) & 7) << 3) + (col & 7);
}

// ---------------- weight convert: fp32 -> bf16 ----------------
__global__ __launch_bounds__(256) void convert_bf16_kernel(const float* __restrict__ src,
                                                           short* __restrict__ dst,
                                                           int n_valid, int n_total) {
    const int i = blockIdx.x * 256 + threadIdx.x;
    if (i < n_total) dst[i] = (i < n_valid) ? f2bf(src[i]) : (short)0;
}

// ---------------- W_out convert with gnorm_w folded ----------------
__global__ __launch_bounds__(256) void convert_wout_kernel(const float* __restrict__ src,
                                                           const float* __restrict__ gw,
                                                           short* __restrict__ dst) {
    const int i = blockIdx.x * 256 + threadIdx.x;
    if (i < DMODEL * DINNER) dst[i] = f2bf(src[i] * gw[i % DINNER]);
}

// ---------------- rmsnorm of x (D=256) -> bf16 xn AND exact fp32 dt (8 heads) ----------
__global__ __launch_bounds__(256) void rmsnorm_dt_kernel(const float* __restrict__ x,
                                                         const float* __restrict__ w,
                                                         const float* __restrict__ W_in,
                                                         short* __restrict__ xn,
                                                         float* __restrict__ dt) {
    const int row  = blockIdx.x * 4 + (threadIdx.x >> 6);
    const int lane = threadIdx.x & 63;
    const float4 v = *(const float4*)(x + (size_t)row * DMODEL + lane * 4);
    float ss = v.x * v.x + v.y * v.y + v.z * v.z + v.w * v.w;
#pragma unroll
    for (int off = 1; off < 64; off <<= 1) ss += __shfl_xor(ss, off);
    const float rs = rsqrtf(ss * (1.0f / DMODEL) + 1.1920929e-7f);
    const float4 wv = *(const float4*)(w + lane * 4);
    const float4 xn4 = make_float4(v.x * rs * wv.x, v.y * rs * wv.y,
                                   v.z * rs * wv.z, v.w * rs * wv.w);
    short4 o;
    o.x = f2bf(xn4.x); o.y = f2bf(xn4.y); o.z = f2bf(xn4.z); o.w = f2bf(xn4.w);
    *(short4*)(xn + (size_t)row * DMODEL + lane * 4) = o;
#pragma unroll
    for (int h = 0; h < NHEADS; ++h) {
        const float4 ww = *(const float4*)(W_in + (size_t)(DPROJ - NHEADS + h) * DMODEL + lane * 4);
        float p = xn4.x * ww.x + xn4.y * ww.y + xn4.z * ww.z + xn4.w * ww.w;
#pragma unroll
        for (int off = 1; off < 64; off <<= 1) p += __shfl_xor(p, off);
        if (lane == 0) dt[(size_t)row * NHEADS + h] = p;
    }
}

// ---------------- bf16 MFMA GEMM: C[M][N] = A[M][K] * B[N][K]^T ----------
template <bool RES, typename OUT>
__global__ __launch_bounds__(256) void gemm_bf16_nt(const short* __restrict__ A,
                                                    const short* __restrict__ B,
                                                    const float* __restrict__ R,
                                                    const float* __restrict__ RS,
                                                    OUT* __restrict__ C,
                                                    int NX, int M, int N, int K, int LDA) {
    const int L   = blockIdx.x;
    const int xcd = L & 7;
    const int r   = L >> 3;
    const int mstrips_per_xcd = (M / 128) >> 3;
    const int mblk = xcd * mstrips_per_xcd + r / NX;
    const int nblk = r % NX;
    const int m0 = mblk * 128, n0 = nblk * 128;

    __shared__ __align__(16) short Asl[128 * 64];   // 16 KB
    __shared__ __align__(16) short Bsl[128 * 64];   // 16 KB
    const int tid  = threadIdx.x;
    const int lane = tid & 63;
    const int wid  = tid >> 6;
    const int wrow = (wid >> 1) * 64, wcol = (wid & 1) * 64;

    f32x4 acc[4][4];
#pragma unroll
    for (int m = 0; m < 4; ++m)
#pragma unroll
        for (int n = 0; n < 4; ++n) acc[m][n] = (f32x4)0.f;

    const int wbase = (tid & 0xC0) * 8;

    for (int k0 = 0; k0 < K; k0 += 64) {
#pragma unroll
        for (int rr = 0; rr < 4; ++rr) {
            const int idx = rr * 256 + tid;
            const int row = idx >> 3;
            const int cs  = idx & 7;
            const int ko  = (cs ^ (row & 7)) * 8;
            const int r6  = row & 63;
            const int brow = (row & 64) + (((r6 & 15) << 2) | (r6 >> 4));
            stage16(A + (size_t)(m0 + row) * LDA + k0 + ko, Asl + rr * 2048 + wbase);
            stage16(B + (size_t)(n0 + brow) * K + k0 + ko, Bsl + rr * 2048 + wbase);
        }
        __syncthreads();
#pragma unroll
        for (int ks = 0; ks < 2; ++ks) {
            bf16x8 af[4], bfr[4];
#pragma unroll
            for (int m = 0; m < 4; ++m) {
                const int arow = wrow + m * 16 + (lane & 15);
                const int ch = (ks * 4 + (lane >> 4)) ^ (arow & 7);
                af[m] = *(const bf16x8*)(Asl + arow * 64 + ch * 8);
            }
#pragma unroll
            for (int n = 0; n < 4; ++n) {
                const int brw = wcol + n * 16 + (lane & 15);
                const int ch = (ks * 4 + (lane >> 4)) ^ (brw & 7);
                bfr[n] = *(const bf16x8*)(Bsl + brw * 64 + ch * 8);
            }
#pragma unroll
            for (int m = 0; m < 4; ++m)
#pragma unroll
                for (int n = 0; n < 4; ++n)
                    acc[m][n] = __builtin_amdgcn_mfma_f32_16x16x32_bf16(af[m], bfr[n], acc[m][n], 0, 0, 0);
        }
        __syncthreads();
    }

    const int r0 = (lane >> 4) * 4;
    const int gcol = n0 + wcol + (lane & 15) * 4;
#pragma unroll
    for (int m = 0; m < 4; ++m) {
        const int grow = m0 + wrow + m * 16 + r0;
        if (gcol < N) {
#pragma unroll
            for (int reg = 0; reg < 4; ++reg) {
                if constexpr (sizeof(OUT) == 2) {
                    short4 o;
                    o.x = f2bf(acc[m][0][reg]); o.y = f2bf(acc[m][1][reg]);
                    o.z = f2bf(acc[m][2][reg]); o.w = f2bf(acc[m][3][reg]);
                    *(short4*)(C + (size_t)(grow + reg) * N + gcol) = o;
                } else {
                    f32x4 v;
                    v[0] = acc[m][0][reg]; v[1] = acc[m][1][reg];
                    v[2] = acc[m][2][reg]; v[3] = acc[m][3][reg];
                    if (RES) {
                        const float* rp = RS + (size_t)(grow + reg) * NHEADS;
                        const f32x4 s0 = *(const f32x4*)rp;
                        const f32x4 s1 = *(const f32x4*)(rp + 4);
                        const float sum = s0[0] + s0[1] + s0[2] + s0[3] +
                                          s1[0] + s1[1] + s1[2] + s1[3];
                        const float rsn = rsqrtf(sum * (1.0f / DINNER) + 1e-5f);
                        v *= rsn;
                        v += *(const f32x4*)(R + (size_t)(grow + reg) * N + gcol);
                    }
                    *(f32x4*)(C + (size_t)(grow + reg) * N + gcol) = v;
                }
            }
        }
    }
}

// ---- depthwise causal conv(4) + bias + SiLU: sliding window, 8 rows x 8 ch per thread ----
__global__ __launch_bounds__(256) void conv_silu_kernel(const short* __restrict__ zxb,
                                                        const float* __restrict__ cw,
                                                        const float* __restrict__ cb,
                                                        short* __restrict__ xbc) {
    const int idx = blockIdx.x * 256 + threadIdx.x;   // over (NROWS/8)*80
    const int c8  = (idx % 80) * 8;
    const int bl0 = (idx / 80) * 8;                   // first of 8 rows
    const int l0  = bl0 & (SEQ - 1);
    const short* src = zxb + (size_t)bl0 * ZSTR + DINNER + c8;

    float4 w4[8];
    float bias[8];
#pragma unroll
    for (int j = 0; j < 8; ++j) w4[j] = *(const float4*)(cw + (c8 + j) * 4);
    {
        const float4 b0 = *(const float4*)(cb + c8);
        const float4 b1 = *(const float4*)(cb + c8 + 4);
        bias[0] = b0.x; bias[1] = b0.y; bias[2] = b0.z; bias[3] = b0.w;
        bias[4] = b1.x; bias[5] = b1.y; bias[6] = b1.z; bias[7] = b1.w;
    }

    bf16x8 rowv[11];                                  // rows l0-3 .. l0+7
#pragma unroll
    for (int m = 0; m < 11; ++m) {
        if (l0 + m - 3 >= 0)
            rowv[m] = *(const bf16x8*)(src + (ptrdiff_t)(m - 3) * ZSTR);
        else
            rowv[m] = (bf16x8)0;
    }

#pragma unroll
    for (int r = 0; r < 8; ++r) {
        float acc[8];
#pragma unroll
        for (int j = 0; j < 8; ++j) acc[j] = bias[j];
#pragma unroll
        for (int k = 0; k < 4; ++k) {
            const bf16x8 tap = rowv[r + k];
#pragma unroll
            for (int j = 0; j < 8; ++j)
                acc[j] = fmaf(bf2f(tap[j]), ((const float*)&w4[j])[k], acc[j]);
        }
        short8v o;
#pragma unroll
        for (int j = 0; j < 8; ++j) {
            const float s = acc[j];
            o[j] = f2bf(s / (1.f + __expf(-s)));
        }
        *(short8v*)(xbc + (size_t)(bl0 + r) * CONVDIM + c8) = o;
    }
}

// ---------------- scan pass 1 (MFMA): L[p][n] = sum_t X[t][p] * (w_t * B[t][n]) ----------
__global__ __launch_bounds__(256) void chunk_state_mfma(const float* __restrict__ dt,
                                                        const short* __restrict__ xbc,
                                                        const float* __restrict__ dt_bias,
                                                        const float* __restrict__ A_log,
                                                        short* __restrict__ lstate,
                                                        float* __restrict__ decayC) {
    const int bhc = blockIdx.x;
    const int c = bhc & (NCHUNK - 1), bh = bhc >> 6, h = bh & (NHEADS - 1), b = bh >> 3;
    const int tid = threadIdx.x, lane = tid & 63, wid = tid >> 6;
    __shared__ short XT[64 * LSTR];   // X^T, slot-permuted
    __shared__ short BT[64 * LSTR];   // (w*B)^T, slot-permuted
    __shared__ float wsh[CHUNK];
    const size_t row0 = (size_t)b * SEQ + (size_t)c * CHUNK;

    const float aneg  = -__expf(A_log[h]);
    const float dbias = dt_bias[h];
    if (tid < 64) {
        const float draw = dt[(row0 + tid) * NHEADS + h] + dbias;
        const float dtv  = (draw > 20.f) ? draw : log1pf(__expf(draw));
        float cum = aneg * dtv;
#pragma unroll
        for (int off = 1; off < 64; off <<= 1) {
            const float nv = __shfl_up(cum, off);
            if (lane >= off) cum += nv;
        }
        const float total = __shfl(cum, 63);
        wsh[tid] = __expf(total - cum) * dtv;
        if (tid == 63) decayC[bhc] = __expf(cum);
    }
    __syncthreads();

#pragma unroll
    for (int r = 0; r < 4; ++r) {
        const int idx  = tid + r * 256;
        const int trow = idx >> 4;
        const int q    = idx & 15;
        const int c4   = q * 4;
        const short* rp = xbc + (row0 + trow) * CONVDIM;
        const short4 xv = *(const short4*)(rp + h * 64 + c4);
        const short4 bv = *(const short4*)(rp + DINNER + c4);
        const float w = wsh[trow];
        XT[(0 * 16 + q) * LSTR + trow] = xv.x;
        XT[(1 * 16 + q) * LSTR + trow] = xv.y;
        XT[(2 * 16 + q) * LSTR + trow] = xv.z;
        XT[(3 * 16 + q) * LSTR + trow] = xv.w;
        BT[(0 * 16 + q) * LSTR + trow] = f2bf(bf2f(bv.x) * w);
        BT[(1 * 16 + q) * LSTR + trow] = f2bf(bf2f(bv.y) * w);
        BT[(2 * 16 + q) * LSTR + trow] = f2bf(bf2f(bv.z) * w);
        BT[(3 * 16 + q) * LSTR + trow] = f2bf(bf2f(bv.w) * w);
    }
    __syncthreads();

    f32x4 acc[4];
#pragma unroll
    for (int n = 0; n < 4; ++n) acc[n] = (f32x4)0.f;
#pragma unroll
    for (int ks = 0; ks < 2; ++ks) {
        const bf16x8 af = *(const bf16x8*)(XT + (wid * 16 + (lane & 15)) * LSTR + ks * 32 + (lane >> 4) * 8);
#pragma unroll
        for (int n = 0; n < 4; ++n) {
            const bf16x8 bfv = *(const bf16x8*)(BT + (n * 16 + (lane & 15)) * LSTR + ks * 32 + (lane >> 4) * 8);
            acc[n] = __builtin_amdgcn_mfma_f32_16x16x32_bf16(af, bfv, acc[n], 0, 0, 0);
        }
    }
    short* lp = lstate + ((size_t)bhc << 12);
    const int hi = lane >> 4;
    const int ncol = (lane & 15) * 4;
#pragma unroll
    for (int reg = 0; reg < 4; ++reg) {
        const int p = 16 * hi + 4 * reg + wid;
        short4 o;
        o.x = f2bf(acc[0][reg]); o.y = f2bf(acc[1][reg]);
        o.z = f2bf(acc[2][reg]); o.w = f2bf(acc[3][reg]);
        *(short4*)(lp + p * 64 + ncol) = o;
    }
}

// ---------------- scan pass 2: inter-chunk recurrence, 1 elem/thread (max TLP) ----------
__global__ __launch_bounds__(256) void state_prefix_kernel(short* __restrict__ lstate,
                                                           const float* __restrict__ decayC) {
    const int idx = blockIdx.x * 256 + threadIdx.x;   // over BATCH*NHEADS*4096
    const int bh = idx >> 12;
    const int pn = idx & 4095;
    float S = 0.f;
    for (int c = 0; c < NCHUNK; ++c) {
        short* ptr = lstate + (((size_t)bh * NCHUNK + c) << 12) + pn;
        const float l = bf2f(*ptr);
        *ptr = f2bf(S);
        S = fmaf(S, decayC[bh * NCHUNK + c], l);
    }
}

// ---- scan pass 3 (MFMA): y = mask(C@B^T)@X + exp(cum)*(C@SP^T) + Dp*X, fused gating.
// XOR-swizzled [64][64] tiles (no pad) -> LDS 32768 B. cums/dt in per-wave registers.
// Epilogue reads x as L2-hot short4 global loads (not LDS readback). ----
__global__ __launch_bounds__(256) void chunk_scan_mfma(const float* __restrict__ dt,
                                                       short* __restrict__ xbc,
                                                       const short* __restrict__ zxb,
                                                       float* __restrict__ rowss,
                                                       const float* __restrict__ dt_bias,
                                                       const float* __restrict__ A_log,
                                                       const float* __restrict__ Dp,
                                                       const short* __restrict__ lstate) {
    const int bhc = blockIdx.x;
    const int c = bhc & (NCHUNK - 1), bh = bhc >> 6, h = bh & (NHEADS - 1), b = bh >> 3;
    const int tid = threadIdx.x, lane = tid & 63, wid = tid >> 6;
    __shared__ short BsMs[64 * 64]; // B rows [t][n]; later masked scores [s][t]
    __shared__ short Cs[64 * 64];   // C rows [s][n]
    __shared__ short XT[64 * 64];   // X^T, slot-permuted
    __shared__ short SP[64 * 64];   // prefix state, slot-permuted
    short* Bs = BsMs;
    short* Ms = BsMs;
    const size_t row0 = (size_t)b * SEQ + (size_t)c * CHUNK;

    // per-wave redundant fp32 prefix of aneg*dt (identical across waves)
    const float aneg  = -__expf(A_log[h]);
    const float dbias = dt_bias[h];
    const float draw = dt[(row0 + lane) * NHEADS + h] + dbias;
    const float dtv  = (draw > 20.f) ? draw : log1pf(__expf(draw));
    float cum = aneg * dtv;
#pragma unroll
    for (int off = 1; off < 64; off <<= 1) {
        const float nv = __shfl_up(cum, off);
        if (lane >= off) cum += nv;
    }

#pragma unroll
    for (int r = 0; r < 4; ++r) {
        const int idx  = tid + r * 256;
        const int trow = idx >> 4;
        const int q    = idx & 15;
        const int c4   = q * 4;
        const short* rp = xbc + (row0 + trow) * CONVDIM;
        const short4 xv = *(const short4*)(rp + h * 64 + c4);
        const int hoff = ((((q >> 1) ^ trow) & 7) << 3) + (q & 1) * 4;
        *(short4*)(Bs + trow * 64 + hoff) = *(const short4*)(rp + DINNER + c4);
        *(short4*)(Cs + trow * 64 + hoff) = *(const short4*)(rp + DINNER + DSTATE + c4);
        // p-row c4+i -> slot (i*16 + q), column trow (swizzled)
        XT[swz(0 * 16 + q, trow)] = xv.x;
        XT[swz(1 * 16 + q, trow)] = xv.y;
        XT[swz(2 * 16 + q, trow)] = xv.z;
        XT[swz(3 * 16 + q, trow)] = xv.w;
    }
#pragma unroll
    for (int r = 0; r < 4; ++r) {
        const int idx = tid + r * 256;
        const int p = idx >> 4, q = idx & 15;
        const int pslot = ((p & 3) << 4) | (p >> 2);
        const int hoff = ((((q >> 1) ^ pslot) & 7) << 3) + (q & 1) * 4;
        *(short4*)(SP + pslot * 64 + hoff) =
            *(const short4*)(lstate + ((size_t)bhc << 12) + p * 64 + q * 4);
    }
    __syncthreads();

    // G = C @ B^T (over n)
    f32x4 accG[4];
#pragma unroll
    for (int tf = 0; tf < 4; ++tf) accG[tf] = (f32x4)0.f;
    __builtin_amdgcn_s_setprio(1);
#pragma unroll
    for (int ks = 0; ks < 2; ++ks) {
        const int crow = wid * 16 + (lane & 15);
        const bf16x8 af = *(const bf16x8*)(Cs + crow * 64 + (((ks * 4 + (lane >> 4)) ^ crow) & 7) * 8);
#pragma unroll
        for (int tf = 0; tf < 4; ++tf) {
            const int brw = tf * 16 + (lane & 15);
            const bf16x8 bfv = *(const bf16x8*)(Bs + brw * 64 + (((ks * 4 + (lane >> 4)) ^ brw) & 7) * 8);
            accG[tf] = __builtin_amdgcn_mfma_f32_16x16x32_bf16(af, bfv, accG[tf], 0, 0, 0);
        }
    }
    __builtin_amdgcn_s_setprio(0);
    __syncthreads();   // all waves done reading Bs before Ms overlays it

    // causal mask + decay scale -> Ms (bf16), overlaid on Bs
    const int srow0 = wid * 16 + (lane >> 4) * 4;
    float csr[4];
#pragma unroll
    for (int reg = 0; reg < 4; ++reg) csr[reg] = __shfl(cum, srow0 + reg);
#pragma unroll
    for (int tf = 0; tf < 4; ++tf) {
        const int t = tf * 16 + (lane & 15);
        const float ct  = __shfl(cum, t);
        const float dtt = __shfl(dtv, t);
#pragma unroll
        for (int reg = 0; reg < 4; ++reg) {
            const int s = srow0 + reg;
            const float m = (t <= s) ? accG[tf][reg] * __expf(csr[reg] - ct) * dtt : 0.f;
            Ms[swz(s, t)] = f2bf(m);
        }
    }
    __syncthreads();

    // Y1 = M @ X ; Y2 = C @ SP^T
    f32x4 acc1[4], acc2[4];
#pragma unroll
    for (int pf = 0; pf < 4; ++pf) { acc1[pf] = (f32x4)0.f; acc2[pf] = (f32x4)0.f; }
    __builtin_amdgcn_s_setprio(1);
#pragma unroll
    for (int ks = 0; ks < 2; ++ks) {
        const int mrow = wid * 16 + (lane & 15);
        const int ch = ks * 4 + (lane >> 4);
        const bf16x8 am = *(const bf16x8*)(Ms + mrow * 64 + ((ch ^ mrow) & 7) * 8);
        const bf16x8 ac = *(const bf16x8*)(Cs + mrow * 64 + ((ch ^ mrow) & 7) * 8);
#pragma unroll
        for (int pf = 0; pf < 4; ++pf) {
            const int prow = pf * 16 + (lane & 15);
            const bf16x8 bx = *(const bf16x8*)(XT + prow * 64 + ((ch ^ prow) & 7) * 8);
            const bf16x8 bs = *(const bf16x8*)(SP + prow * 64 + ((ch ^ prow) & 7) * 8);
            acc1[pf] = __builtin_amdgcn_mfma_f32_16x16x32_bf16(am, bx, acc1[pf], 0, 0, 0);
            acc2[pf] = __builtin_amdgcn_mfma_f32_16x16x32_bf16(ac, bs, acc2[pf], 0, 0, 0);
        }
    }
    __builtin_amdgcn_s_setprio(0);
    const float dpv = Dp[h];
    float es[4];
#pragma unroll
    for (int reg = 0; reg < 4; ++reg) es[reg] = __expf(csr[reg]);
    const int j = lane & 15;
#pragma unroll
    for (int reg = 0; reg < 4; ++reg) {
        const int s = srow0 + reg;
        const short4 z4 = *(const short4*)(zxb + (row0 + s) * ZSTR + h * 64 + j * 4);
        const short4 x4 = *(const short4*)(xbc + (row0 + s) * CONVDIM + h * 64 + j * 4);
        short4 o;
        float ssq = 0.f;
#pragma unroll
        for (int pf = 0; pf < 4; ++pf) {
            const float xv = bf2f(((const short*)&x4)[pf]);
            const float yv = acc1[pf][reg] + es[reg] * acc2[pf][reg] + dpv * xv;
            const float zf = bf2f(((const short*)&z4)[pf]);
            const float v  = yv * zf / (1.f + __expf(-zf));
            ((short*)&o)[pf] = f2bf(v);
            ssq = fmaf(v, v, ssq);
        }
        *(short4*)(xbc + (row0 + s) * CONVDIM + h * 64 + j * 4) = o;
        ssq += __shfl_xor(ssq, 1);
        ssq += __shfl_xor(ssq, 2);
        ssq += __shfl_xor(ssq, 4);
        ssq += __shfl_xor(ssq, 8);
        if (j == 0) rowss[(row0 + s) * NHEADS + h] = ssq;
    }
}

// ---------------- launch ----------------
extern "C" void kernel_launch(void* const* d_in, const int* in_sizes, int n_in,
                              void* d_out, int out_size, void* d_ws, size_t ws_size,
                              hipStream_t stream) {
    (void)in_sizes; (void)n_in; (void)out_size; (void)d_ws; (void)ws_size;
    const float* x      = (const float*)d_in[0];
    const float* W_in   = (const float*)d_in[1];
    const float* conv_w = (const float*)d_in[2];
    const float* conv_b = (const float*)d_in[3];
    const float* dt_b   = (const float*)d_in[4];
    const float* A_log  = (const float*)d_in[5];
    const float* Dp     = (const float*)d_in[6];
    const float* g_w    = (const float*)d_in[7];
    const float* n_w    = (const float*)d_in[8];
    const float* W_out  = (const float*)d_in[9];
    float* out = (float*)d_out;

    short *xn, *zxb, *xbc, *winb, *woutb, *lst;
    float *dtv, *dcy, *rss;
    hipGetSymbolAddress((void**)&xn,    HIP_SYMBOL(g_xn));
    hipGetSymbolAddress((void**)&zxb,   HIP_SYMBOL(g_zxb));
    hipGetSymbolAddress((void**)&xbc,   HIP_SYMBOL(g_xbc));
    hipGetSymbolAddress((void**)&dtv,   HIP_SYMBOL(g_dt));
    hipGetSymbolAddress((void**)&rss,   HIP_SYMBOL(g_rowss));
    hipGetSymbolAddress((void**)&lst,   HIP_SYMBOL(g_lstate));
    hipGetSymbolAddress((void**)&dcy,   HIP_SYMBOL(g_decayC));
    hipGetSymbolAddress((void**)&winb,  HIP_SYMBOL(g_Winb));
    hipGetSymbolAddress((void**)&woutb, HIP_SYMBOL(g_Woutb));

    convert_bf16_kernel<<<(ZSTR * DMODEL) / 256, 256, 0, stream>>>(
        W_in, winb, ZSTR * DMODEL, ZSTR * DMODEL);
    convert_wout_kernel<<<(DMODEL * DINNER) / 256, 256, 0, stream>>>(W_out, g_w, woutb);

    rmsnorm_dt_kernel<<<NROWS / 4, 256, 0, stream>>>(x, n_w, W_in, xn, dtv);

    gemm_bf16_nt<false, short><<<(ZSTR / 128) * (NROWS / 128), 256, 0, stream>>>(
        xn, winb, nullptr, nullptr, zxb, ZSTR / 128, NROWS, ZSTR, DMODEL, DMODEL);

    conv_silu_kernel<<<(NROWS / 8 * 80) / 256, 256, 0, stream>>>(zxb, conv_w, conv_b, xbc);

    chunk_state_mfma<<<BATCH * NHEADS * NCHUNK, 256, 0, stream>>>(dtv, xbc, dt_b, A_log, lst, dcy);
    state_prefix_kernel<<<(BATCH * NHEADS * HEADDIM * DSTATE) / 256, 256, 0, stream>>>(lst, dcy);
    chunk_scan_mfma<<<BATCH * NHEADS * NCHUNK, 256, 0, stream>>>(
        dtv, xbc, zxb, rss, dt_b, A_log, Dp, lst);

    gemm_bf16_nt<true, float><<<(DMODEL / 128) * (NROWS / 128), 256, 0, stream>>>(
        xbc, woutb, x, rss, out, DMODEL / 128, NROWS, DMODEL, DINNER, CONVDIM);
}

// Round 17
// 176.652 us; speedup vs baseline: 1.0437x; 1.0137x over previous
//
#include <hip/hip_runtime.h>
#include <math.h>

#define BATCH   8
#define SEQ     4096
#define DMODEL  256
#define DINNER  512
#define DSTATE  64
#define NHEADS  8
#define HEADDIM 64
#define CONVDIM 640          // DINNER + 2*DSTATE
#define DPROJ   1160         // full in-proj rows (for W_in/dt indexing)
#define ZSTR    1152         // z | xBC columns actually materialized (9*128)
#define NROWS   (BATCH*SEQ)  // 32768
#define CHUNK   64
#define NCHUNK  (SEQ/CHUNK)  // 64
#define LSTR    72           // LDS row stride for chunk_state (shorts)

typedef short bf16x8 __attribute__((ext_vector_type(8)));
typedef short short8v __attribute__((ext_vector_type(8)));
typedef float f32x4 __attribute__((ext_vector_type(4)));

// ---- static workspace (BSS) ----
__device__ short g_xn[(size_t)NROWS * DMODEL];      // bf16 16.8 MB
__device__ short g_zxb[(size_t)NROWS * ZSTR];       // bf16 75.5 MB (z | xBC)
__device__ short g_xbc[(size_t)NROWS * CONVDIM];    // bf16 42.0 MB (conv out; x-slice overwritten by gated v)
__device__ float g_dt[(size_t)NROWS * NHEADS];      // fp32  1.0 MB (raw dt, pre-bias)
__device__ float g_rowss[(size_t)NROWS * NHEADS];   // fp32  1.0 MB (per-row per-head sum of v^2)
__device__ short g_lstate[(size_t)BATCH * NHEADS * NCHUNK * HEADDIM * DSTATE]; // bf16 33.5 MB
__device__ float g_decayC[BATCH * NHEADS * NCHUNK];
__device__ short g_Winb[(size_t)ZSTR * DMODEL];     // bf16 W_in rows 0..1151
__device__ short g_Woutb[(size_t)DMODEL * DINNER];  // bf16 W_out * gnorm_w

__device__ __forceinline__ short f2bf(float f) {
    unsigned u = __float_as_uint(f);
    u += 0x7fff + ((u >> 16) & 1);
    return (short)(u >> 16);
}
__device__ __forceinline__ float bf2f(short s) {
    return __uint_as_float(((unsigned)(unsigned short)s) << 16);
}

__device__ __forceinline__ void stage16(const void* gsrc, void* ldst) {
    __builtin_amdgcn_global_load_lds(
        (const __attribute__((address_space(1))) void*)gsrc,
        (__attribute__((address_space(3))) void*)ldst, 16, 0, 0);
}

// element offset in a [64][64] bf16 tile with XOR chunk swizzle
__device__ __forceinline__ int swz(int row, int col) {
    return row * 64 + ((((col >> 3) ^ row) & 7) << 3) + (col & 7);
}

// ---------------- weight convert: fp32 -> bf16 ----------------
__global__ __launch_bounds__(256) void convert_bf16_kernel(const float* __restrict__ src,
                                                           short* __restrict__ dst,
                                                           int n_valid, int n_total) {
    const int i = blockIdx.x * 256 + threadIdx.x;
    if (i < n_total) dst[i] = (i < n_valid) ? f2bf(src[i]) : (short)0;
}

// ---------------- W_out convert with gnorm_w folded ----------------
__global__ __launch_bounds__(256) void convert_wout_kernel(const float* __restrict__ src,
                                                           const float* __restrict__ gw,
                                                           short* __restrict__ dst) {
    const int i = blockIdx.x * 256 + threadIdx.x;
    if (i < DMODEL * DINNER) dst[i] = f2bf(src[i] * gw[i % DINNER]);
}

// ---------------- rmsnorm of x (D=256) -> bf16 xn AND exact fp32 dt (8 heads) ----------
__global__ __launch_bounds__(256) void rmsnorm_dt_kernel(const float* __restrict__ x,
                                                         const float* __restrict__ w,
                                                         const float* __restrict__ W_in,
                                                         short* __restrict__ xn,
                                                         float* __restrict__ dt) {
    const int row  = blockIdx.x * 4 + (threadIdx.x >> 6);
    const int lane = threadIdx.x & 63;
    const float4 v = *(const float4*)(x + (size_t)row * DMODEL + lane * 4);
    float ss = v.x * v.x + v.y * v.y + v.z * v.z + v.w * v.w;
#pragma unroll
    for (int off = 1; off < 64; off <<= 1) ss += __shfl_xor(ss, off);
    const float rs = rsqrtf(ss * (1.0f / DMODEL) + 1.1920929e-7f);
    const float4 wv = *(const float4*)(w + lane * 4);
    const float4 xn4 = make_float4(v.x * rs * wv.x, v.y * rs * wv.y,
                                   v.z * rs * wv.z, v.w * rs * wv.w);
    short4 o;
    o.x = f2bf(xn4.x); o.y = f2bf(xn4.y); o.z = f2bf(xn4.z); o.w = f2bf(xn4.w);
    *(short4*)(xn + (size_t)row * DMODEL + lane * 4) = o;
#pragma unroll
    for (int h = 0; h < NHEADS; ++h) {
        const float4 ww = *(const float4*)(W_in + (size_t)(DPROJ - NHEADS + h) * DMODEL + lane * 4);
        float p = xn4.x * ww.x + xn4.y * ww.y + xn4.z * ww.z + xn4.w * ww.w;
#pragma unroll
        for (int off = 1; off < 64; off <<= 1) p += __shfl_xor(p, off);
        if (lane == 0) dt[(size_t)row * NHEADS + h] = p;
    }
}

// ---------------- bf16 MFMA GEMM: C[M][N] = A[M][K] * B[N][K]^T ----------
template <bool RES, typename OUT>
__global__ __launch_bounds__(256) void gemm_bf16_nt(const short* __restrict__ A,
                                                    const short* __restrict__ B,
                                                    const float* __restrict__ R,
                                                    const float* __restrict__ RS,
                                                    OUT* __restrict__ C,
                                                    int NX, int M, int N, int K, int LDA) {
    const int L   = blockIdx.x;
    const int xcd = L & 7;
    const int r   = L >> 3;
    const int mstrips_per_xcd = (M / 128) >> 3;
    const int mblk = xcd * mstrips_per_xcd + r / NX;
    const int nblk = r % NX;
    const int m0 = mblk * 128, n0 = nblk * 128;

    __shared__ __align__(16) short Asl[128 * 64];   // 16 KB
    __shared__ __align__(16) short Bsl[128 * 64];   // 16 KB
    const int tid  = threadIdx.x;
    const int lane = tid & 63;
    const int wid  = tid >> 6;
    const int wrow = (wid >> 1) * 64, wcol = (wid & 1) * 64;

    f32x4 acc[4][4];
#pragma unroll
    for (int m = 0; m < 4; ++m)
#pragma unroll
        for (int n = 0; n < 4; ++n) acc[m][n] = (f32x4)0.f;

    const int wbase = (tid & 0xC0) * 8;

    for (int k0 = 0; k0 < K; k0 += 64) {
#pragma unroll
        for (int rr = 0; rr < 4; ++rr) {
            const int idx = rr * 256 + tid;
            const int row = idx >> 3;
            const int cs  = idx & 7;
            const int ko  = (cs ^ (row & 7)) * 8;
            const int r6  = row & 63;
            const int brow = (row & 64) + (((r6 & 15) << 2) | (r6 >> 4));
            stage16(A + (size_t)(m0 + row) * LDA + k0 + ko, Asl + rr * 2048 + wbase);
            stage16(B + (size_t)(n0 + brow) * K + k0 + ko, Bsl + rr * 2048 + wbase);
        }
        __syncthreads();
#pragma unroll
        for (int ks = 0; ks < 2; ++ks) {
            bf16x8 af[4], bfr[4];
#pragma unroll
            for (int m = 0; m < 4; ++m) {
                const int arow = wrow + m * 16 + (lane & 15);
                const int ch = (ks * 4 + (lane >> 4)) ^ (arow & 7);
                af[m] = *(const bf16x8*)(Asl + arow * 64 + ch * 8);
            }
#pragma unroll
            for (int n = 0; n < 4; ++n) {
                const int brw = wcol + n * 16 + (lane & 15);
                const int ch = (ks * 4 + (lane >> 4)) ^ (brw & 7);
                bfr[n] = *(const bf16x8*)(Bsl + brw * 64 + ch * 8);
            }
#pragma unroll
            for (int m = 0; m < 4; ++m)
#pragma unroll
                for (int n = 0; n < 4; ++n)
                    acc[m][n] = __builtin_amdgcn_mfma_f32_16x16x32_bf16(af[m], bfr[n], acc[m][n], 0, 0, 0);
        }
        __syncthreads();
    }

    const int r0 = (lane >> 4) * 4;
    const int gcol = n0 + wcol + (lane & 15) * 4;
#pragma unroll
    for (int m = 0; m < 4; ++m) {
        const int grow = m0 + wrow + m * 16 + r0;
        if (gcol < N) {
#pragma unroll
            for (int reg = 0; reg < 4; ++reg) {
                if constexpr (sizeof(OUT) == 2) {
                    short4 o;
                    o.x = f2bf(acc[m][0][reg]); o.y = f2bf(acc[m][1][reg]);
                    o.z = f2bf(acc[m][2][reg]); o.w = f2bf(acc[m][3][reg]);
                    *(short4*)(C + (size_t)(grow + reg) * N + gcol) = o;
                } else {
                    f32x4 v;
                    v[0] = acc[m][0][reg]; v[1] = acc[m][1][reg];
                    v[2] = acc[m][2][reg]; v[3] = acc[m][3][reg];
                    if (RES) {
                        const float* rp = RS + (size_t)(grow + reg) * NHEADS;
                        const f32x4 s0 = *(const f32x4*)rp;
                        const f32x4 s1 = *(const f32x4*)(rp + 4);
                        const float sum = s0[0] + s0[1] + s0[2] + s0[3] +
                                          s1[0] + s1[1] + s1[2] + s1[3];
                        const float rsn = rsqrtf(sum * (1.0f / DINNER) + 1e-5f);
                        v *= rsn;
                        v += *(const f32x4*)(R + (size_t)(grow + reg) * N + gcol);
                    }
                    *(f32x4*)(C + (size_t)(grow + reg) * N + gcol) = v;
                }
            }
        }
    }
}

// ---- depthwise causal conv(4) + bias + SiLU: sliding window, 8 rows x 8 ch per thread ----
__global__ __launch_bounds__(256) void conv_silu_kernel(const short* __restrict__ zxb,
                                                        const float* __restrict__ cw,
                                                        const float* __restrict__ cb,
                                                        short* __restrict__ xbc) {
    const int idx = blockIdx.x * 256 + threadIdx.x;   // over (NROWS/8)*80
    const int c8  = (idx % 80) * 8;
    const int bl0 = (idx / 80) * 8;                   // first of 8 rows
    const int l0  = bl0 & (SEQ - 1);
    const short* src = zxb + (size_t)bl0 * ZSTR + DINNER + c8;

    float4 w4[8];
    float bias[8];
#pragma unroll
    for (int j = 0; j < 8; ++j) w4[j] = *(const float4*)(cw + (c8 + j) * 4);
    {
        const float4 b0 = *(const float4*)(cb + c8);
        const float4 b1 = *(const float4*)(cb + c8 + 4);
        bias[0] = b0.x; bias[1] = b0.y; bias[2] = b0.z; bias[3] = b0.w;
        bias[4] = b1.x; bias[5] = b1.y; bias[6] = b1.z; bias[7] = b1.w;
    }

    bf16x8 rowv[11];                                  // rows l0-3 .. l0+7
#pragma unroll
    for (int m = 0; m < 11; ++m) {
        if (l0 + m - 3 >= 0)
            rowv[m] = *(const bf16x8*)(src + (ptrdiff_t)(m - 3) * ZSTR);
        else
            rowv[m] = (bf16x8)0;
    }

#pragma unroll
    for (int r = 0; r < 8; ++r) {
        float acc[8];
#pragma unroll
        for (int j = 0; j < 8; ++j) acc[j] = bias[j];
#pragma unroll
        for (int k = 0; k < 4; ++k) {
            const bf16x8 tap = rowv[r + k];
#pragma unroll
            for (int j = 0; j < 8; ++j)
                acc[j] = fmaf(bf2f(tap[j]), ((const float*)&w4[j])[k], acc[j]);
        }
        short8v o;
#pragma unroll
        for (int j = 0; j < 8; ++j) {
            const float s = acc[j];
            o[j] = f2bf(s / (1.f + __expf(-s)));
        }
        *(short8v*)(xbc + (size_t)(bl0 + r) * CONVDIM + c8) = o;
    }
}

// ---------------- scan pass 1 (MFMA): L[p][n] = sum_t X[t][p] * (w_t * B[t][n]) ----------
// Per-wave redundant prefix (no wsh LDS / extra barrier); w fetched via __shfl.
__global__ __launch_bounds__(256) void chunk_state_mfma(const float* __restrict__ dt,
                                                        const short* __restrict__ xbc,
                                                        const float* __restrict__ dt_bias,
                                                        const float* __restrict__ A_log,
                                                        short* __restrict__ lstate,
                                                        float* __restrict__ decayC) {
    const int bhc = blockIdx.x;
    const int c = bhc & (NCHUNK - 1), bh = bhc >> 6, h = bh & (NHEADS - 1), b = bh >> 3;
    const int tid = threadIdx.x, lane = tid & 63, wid = tid >> 6;
    __shared__ short XT[64 * LSTR];   // X^T, slot-permuted
    __shared__ short BT[64 * LSTR];   // (w*B)^T, slot-permuted
    const size_t row0 = (size_t)b * SEQ + (size_t)c * CHUNK;

    const float aneg  = -__expf(A_log[h]);
    const float dbias = dt_bias[h];
    const float draw = dt[(row0 + lane) * NHEADS + h] + dbias;
    const float dtv  = (draw > 20.f) ? draw : log1pf(__expf(draw));
    float cum = aneg * dtv;
#pragma unroll
    for (int off = 1; off < 64; off <<= 1) {
        const float nv = __shfl_up(cum, off);
        if (lane >= off) cum += nv;
    }
    const float total = __shfl(cum, 63);
    const float wval  = __expf(total - cum) * dtv;
    if (tid == 63) decayC[bhc] = __expf(total);

#pragma unroll
    for (int r = 0; r < 4; ++r) {
        const int idx  = tid + r * 256;
        const int trow = idx >> 4;
        const int q    = idx & 15;
        const int c4   = q * 4;
        const short* rp = xbc + (row0 + trow) * CONVDIM;
        const short4 xv = *(const short4*)(rp + h * 64 + c4);
        const short4 bv = *(const short4*)(rp + DINNER + c4);
        const float w = __shfl(wval, trow);
        XT[(0 * 16 + q) * LSTR + trow] = xv.x;
        XT[(1 * 16 + q) * LSTR + trow] = xv.y;
        XT[(2 * 16 + q) * LSTR + trow] = xv.z;
        XT[(3 * 16 + q) * LSTR + trow] = xv.w;
        BT[(0 * 16 + q) * LSTR + trow] = f2bf(bf2f(bv.x) * w);
        BT[(1 * 16 + q) * LSTR + trow] = f2bf(bf2f(bv.y) * w);
        BT[(2 * 16 + q) * LSTR + trow] = f2bf(bf2f(bv.z) * w);
        BT[(3 * 16 + q) * LSTR + trow] = f2bf(bf2f(bv.w) * w);
    }
    __syncthreads();

    f32x4 acc[4];
#pragma unroll
    for (int n = 0; n < 4; ++n) acc[n] = (f32x4)0.f;
#pragma unroll
    for (int ks = 0; ks < 2; ++ks) {
        const bf16x8 af = *(const bf16x8*)(XT + (wid * 16 + (lane & 15)) * LSTR + ks * 32 + (lane >> 4) * 8);
#pragma unroll
        for (int n = 0; n < 4; ++n) {
            const bf16x8 bfv = *(const bf16x8*)(BT + (n * 16 + (lane & 15)) * LSTR + ks * 32 + (lane >> 4) * 8);
            acc[n] = __builtin_amdgcn_mfma_f32_16x16x32_bf16(af, bfv, acc[n], 0, 0, 0);
        }
    }
    short* lp = lstate + ((size_t)bhc << 12);
    const int hi = lane >> 4;
    const int ncol = (lane & 15) * 4;
#pragma unroll
    for (int reg = 0; reg < 4; ++reg) {
        const int p = 16 * hi + 4 * reg + wid;
        short4 o;
        o.x = f2bf(acc[0][reg]); o.y = f2bf(acc[1][reg]);
        o.z = f2bf(acc[2][reg]); o.w = f2bf(acc[3][reg]);
        *(short4*)(lp + p * 64 + ncol) = o;
    }
}

// ---------------- scan pass 2: inter-chunk recurrence, short4-wide ----------
__global__ __launch_bounds__(256) void state_prefix_kernel(short* __restrict__ lstate,
                                                           const float* __restrict__ decayC) {
    const int idx = blockIdx.x * 256 + threadIdx.x;
    const int bh  = idx >> 10;
    const int pn4 = (idx & 1023) * 4;
    float S0 = 0.f, S1 = 0.f, S2 = 0.f, S3 = 0.f;
    for (int c = 0; c < NCHUNK; ++c) {
        short4* ptr = (short4*)(lstate + (((size_t)bh * NCHUNK + c) << 12) + pn4);
        const short4 l4 = *ptr;
        short4 o;
        o.x = f2bf(S0); o.y = f2bf(S1); o.z = f2bf(S2); o.w = f2bf(S3);
        *ptr = o;
        const float d = decayC[bh * NCHUNK + c];
        S0 = fmaf(S0, d, bf2f(l4.x));
        S1 = fmaf(S1, d, bf2f(l4.y));
        S2 = fmaf(S2, d, bf2f(l4.z));
        S3 = fmaf(S3, d, bf2f(l4.w));
    }
}

// ---- scan pass 3 (MFMA): y = mask(C@B^T)@X + exp(cum)*(C@SP^T) + Dp*X, fused gating.
// XOR-swizzled [64][64] tiles (no pad) -> LDS 32768 B. cums/dt in per-wave registers.
// Mask uses DIRECT exp(cum_s - cum_t) (arg <= 0, underflow-safe; r16's factored
// form overflowed: exp(-cum) -> inf when cum < -88). ----
__global__ __launch_bounds__(256) void chunk_scan_mfma(const float* __restrict__ dt,
                                                       short* __restrict__ xbc,
                                                       const short* __restrict__ zxb,
                                                       float* __restrict__ rowss,
                                                       const float* __restrict__ dt_bias,
                                                       const float* __restrict__ A_log,
                                                       const float* __restrict__ Dp,
                                                       const short* __restrict__ lstate) {
    const int bhc = blockIdx.x;
    const int c = bhc & (NCHUNK - 1), bh = bhc >> 6, h = bh & (NHEADS - 1), b = bh >> 3;
    const int tid = threadIdx.x, lane = tid & 63, wid = tid >> 6;
    __shared__ short BsMs[64 * 64]; // B rows [t][n]; later masked scores [s][t]
    __shared__ short Cs[64 * 64];   // C rows [s][n]
    __shared__ short XT[64 * 64];   // X^T, slot-permuted
    __shared__ short SP[64 * 64];   // prefix state, slot-permuted
    short* Bs = BsMs;
    short* Ms = BsMs;
    const size_t row0 = (size_t)b * SEQ + (size_t)c * CHUNK;

    // per-wave redundant fp32 prefix of aneg*dt (identical across waves)
    const float aneg  = -__expf(A_log[h]);
    const float dbias = dt_bias[h];
    const float draw = dt[(row0 + lane) * NHEADS + h] + dbias;
    const float dtv  = (draw > 20.f) ? draw : log1pf(__expf(draw));
    float cum = aneg * dtv;
#pragma unroll
    for (int off = 1; off < 64; off <<= 1) {
        const float nv = __shfl_up(cum, off);
        if (lane >= off) cum += nv;
    }

#pragma unroll
    for (int r = 0; r < 4; ++r) {
        const int idx  = tid + r * 256;
        const int trow = idx >> 4;
        const int q    = idx & 15;
        const int c4   = q * 4;
        const short* rp = xbc + (row0 + trow) * CONVDIM;
        const short4 xv = *(const short4*)(rp + h * 64 + c4);
        const int hoff = ((((q >> 1) ^ trow) & 7) << 3) + (q & 1) * 4;
        *(short4*)(Bs + trow * 64 + hoff) = *(const short4*)(rp + DINNER + c4);
        *(short4*)(Cs + trow * 64 + hoff) = *(const short4*)(rp + DINNER + DSTATE + c4);
        XT[swz(0 * 16 + q, trow)] = xv.x;
        XT[swz(1 * 16 + q, trow)] = xv.y;
        XT[swz(2 * 16 + q, trow)] = xv.z;
        XT[swz(3 * 16 + q, trow)] = xv.w;
    }
#pragma unroll
    for (int r = 0; r < 4; ++r) {
        const int idx = tid + r * 256;
        const int p = idx >> 4, q = idx & 15;
        const int pslot = ((p & 3) << 4) | (p >> 2);
        const int hoff = ((((q >> 1) ^ pslot) & 7) << 3) + (q & 1) * 4;
        *(short4*)(SP + pslot * 64 + hoff) =
            *(const short4*)(lstate + ((size_t)bhc << 12) + p * 64 + q * 4);
    }
    __syncthreads();

    // G = C @ B^T (over n)
    f32x4 accG[4];
#pragma unroll
    for (int tf = 0; tf < 4; ++tf) accG[tf] = (f32x4)0.f;
    __builtin_amdgcn_s_setprio(1);
#pragma unroll
    for (int ks = 0; ks < 2; ++ks) {
        const int crow = wid * 16 + (lane & 15);
        const bf16x8 af = *(const bf16x8*)(Cs + crow * 64 + (((ks * 4 + (lane >> 4)) ^ crow) & 7) * 8);
#pragma unroll
        for (int tf = 0; tf < 4; ++tf) {
            const int brw = tf * 16 + (lane & 15);
            const bf16x8 bfv = *(const bf16x8*)(Bs + brw * 64 + (((ks * 4 + (lane >> 4)) ^ brw) & 7) * 8);
            accG[tf] = __builtin_amdgcn_mfma_f32_16x16x32_bf16(af, bfv, accG[tf], 0, 0, 0);
        }
    }
    __builtin_amdgcn_s_setprio(0);
    __syncthreads();   // all waves done reading Bs before Ms overlays it

    // causal mask + decay scale -> Ms (bf16), overlaid on Bs
    const int srow0 = wid * 16 + (lane >> 4) * 4;
    float csr[4];
#pragma unroll
    for (int reg = 0; reg < 4; ++reg) csr[reg] = __shfl(cum, srow0 + reg);
#pragma unroll
    for (int tf = 0; tf < 4; ++tf) {
        const int t = tf * 16 + (lane & 15);
        const float ct  = __shfl(cum, t);
        const float dtt = __shfl(dtv, t);
#pragma unroll
        for (int reg = 0; reg < 4; ++reg) {
            const int s = srow0 + reg;
            const float m = (t <= s) ? accG[tf][reg] * __expf(csr[reg] - ct) * dtt : 0.f;
            Ms[swz(s, t)] = f2bf(m);
        }
    }
    __syncthreads();

    // Y1 = M @ X ; Y2 = C @ SP^T
    f32x4 acc1[4], acc2[4];
#pragma unroll
    for (int pf = 0; pf < 4; ++pf) { acc1[pf] = (f32x4)0.f; acc2[pf] = (f32x4)0.f; }
    __builtin_amdgcn_s_setprio(1);
#pragma unroll
    for (int ks = 0; ks < 2; ++ks) {
        const int mrow = wid * 16 + (lane & 15);
        const int ch = ks * 4 + (lane >> 4);
        const bf16x8 am = *(const bf16x8*)(Ms + mrow * 64 + ((ch ^ mrow) & 7) * 8);
        const bf16x8 ac = *(const bf16x8*)(Cs + mrow * 64 + ((ch ^ mrow) & 7) * 8);
#pragma unroll
        for (int pf = 0; pf < 4; ++pf) {
            const int prow = pf * 16 + (lane & 15);
            const bf16x8 bx = *(const bf16x8*)(XT + prow * 64 + ((ch ^ prow) & 7) * 8);
            const bf16x8 bs = *(const bf16x8*)(SP + prow * 64 + ((ch ^ prow) & 7) * 8);
            acc1[pf] = __builtin_amdgcn_mfma_f32_16x16x32_bf16(am, bx, acc1[pf], 0, 0, 0);
            acc2[pf] = __builtin_amdgcn_mfma_f32_16x16x32_bf16(ac, bs, acc2[pf], 0, 0, 0);
        }
    }
    __builtin_amdgcn_s_setprio(0);
    const float dpv = Dp[h];
    float es[4];
#pragma unroll
    for (int reg = 0; reg < 4; ++reg) es[reg] = __expf(csr[reg]);
    const int j = lane & 15;
#pragma unroll
    for (int reg = 0; reg < 4; ++reg) {
        const int s = srow0 + reg;
        const short4 z4 = *(const short4*)(zxb + (row0 + s) * ZSTR + h * 64 + j * 4);
        short4 o;
        float ssq = 0.f;
#pragma unroll
        for (int pf = 0; pf < 4; ++pf) {
            const float xv = bf2f(XT[swz(pf * 16 + j, s)]);
            const float yv = acc1[pf][reg] + es[reg] * acc2[pf][reg] + dpv * xv;
            const float zf = bf2f(((const short*)&z4)[pf]);
            const float v  = yv * zf / (1.f + __expf(-zf));
            ((short*)&o)[pf] = f2bf(v);
            ssq = fmaf(v, v, ssq);
        }
        *(short4*)(xbc + (row0 + s) * CONVDIM + h * 64 + j * 4) = o;
        ssq += __shfl_xor(ssq, 1);
        ssq += __shfl_xor(ssq, 2);
        ssq += __shfl_xor(ssq, 4);
        ssq += __shfl_xor(ssq, 8);
        if (j == 0) rowss[(row0 + s) * NHEADS + h] = ssq;
    }
}

// ---------------- launch ----------------
extern "C" void kernel_launch(void* const* d_in, const int* in_sizes, int n_in,
                              void* d_out, int out_size, void* d_ws, size_t ws_size,
                              hipStream_t stream) {
    (void)in_sizes; (void)n_in; (void)out_size; (void)d_ws; (void)ws_size;
    const float* x      = (const float*)d_in[0];
    const float* W_in   = (const float*)d_in[1];
    const float* conv_w = (const float*)d_in[2];
    const float* conv_b = (const float*)d_in[3];
    const float* dt_b   = (const float*)d_in[4];
    const float* A_log  = (const float*)d_in[5];
    const float* Dp     = (const float*)d_in[6];
    const float* g_w    = (const float*)d_in[7];
    const float* n_w    = (const float*)d_in[8];
    const float* W_out  = (const float*)d_in[9];
    float* out = (float*)d_out;

    short *xn, *zxb, *xbc, *winb, *woutb, *lst;
    float *dtv, *dcy, *rss;
    hipGetSymbolAddress((void**)&xn,    HIP_SYMBOL(g_xn));
    hipGetSymbolAddress((void**)&zxb,   HIP_SYMBOL(g_zxb));
    hipGetSymbolAddress((void**)&xbc,   HIP_SYMBOL(g_xbc));
    hipGetSymbolAddress((void**)&dtv,   HIP_SYMBOL(g_dt));
    hipGetSymbolAddress((void**)&rss,   HIP_SYMBOL(g_rowss));
    hipGetSymbolAddress((void**)&lst,   HIP_SYMBOL(g_lstate));
    hipGetSymbolAddress((void**)&dcy,   HIP_SYMBOL(g_decayC));
    hipGetSymbolAddress((void**)&winb,  HIP_SYMBOL(g_Winb));
    hipGetSymbolAddress((void**)&woutb, HIP_SYMBOL(g_Woutb));

    convert_bf16_kernel<<<(ZSTR * DMODEL) / 256, 256, 0, stream>>>(
        W_in, winb, ZSTR * DMODEL, ZSTR * DMODEL);
    convert_wout_kernel<<<(DMODEL * DINNER) / 256, 256, 0, stream>>>(W_out, g_w, woutb);

    rmsnorm_dt_kernel<<<NROWS / 4, 256, 0, stream>>>(x, n_w, W_in, xn, dtv);

    gemm_bf16_nt<false, short><<<(ZSTR / 128) * (NROWS / 128), 256, 0, stream>>>(
        xn, winb, nullptr, nullptr, zxb, ZSTR / 128, NROWS, ZSTR, DMODEL, DMODEL);

    conv_silu_kernel<<<(NROWS / 8 * 80) / 256, 256, 0, stream>>>(zxb, conv_w, conv_b, xbc);

    chunk_state_mfma<<<BATCH * NHEADS * NCHUNK, 256, 0, stream>>>(dtv, xbc, dt_b, A_log, lst, dcy);
    state_prefix_kernel<<<(BATCH * NHEADS * HEADDIM * DSTATE) / (4 * 256), 256, 0, stream>>>(lst, dcy);
    chunk_scan_mfma<<<BATCH * NHEADS * NCHUNK, 256, 0, stream>>>(
        dtv, xbc, zxb, rss, dt_b, A_log, Dp, lst);

    gemm_bf16_nt<true, float><<<(DMODEL / 128) * (NROWS / 128), 256, 0, stream>>>(
        xbc, woutb, x, rss, out, DMODEL / 128, NROWS, DMODEL, DINNER, CONVDIM);
}

// Round 18
// 170.776 us; speedup vs baseline: 1.0796x; 1.0344x over previous
//
#include <hip/hip_runtime.h>
#include <math.h>

#define BATCH   8
#define SEQ     4096
#define DMODEL  256
#define DINNER  512
#define DSTATE  64
#define NHEADS  8
#define HEADDIM 64
#define CONVDIM 640          // DINNER + 2*DSTATE
#define DPROJ   1160         // full in-proj rows (for W_in/dt indexing)
#define ZSTR    1152         // z | xBC columns actually materialized (9*128)
#define NROWS   (BATCH*SEQ)  // 32768
#define CHUNK   64
#define NCHUNK  (SEQ/CHUNK)  // 64
#define LSTR    72           // LDS row stride for chunk_state (shorts)

typedef short bf16x8 __attribute__((ext_vector_type(8)));
typedef short short8v __attribute__((ext_vector_type(8)));
typedef float f32x4 __attribute__((ext_vector_type(4)));

// ---- static workspace (BSS) ----
__device__ short g_xn[(size_t)NROWS * DMODEL];      // bf16 16.8 MB
__device__ short g_zxb[(size_t)NROWS * ZSTR];       // bf16 75.5 MB (z | xBC)
__device__ short g_xbc[(size_t)NROWS * CONVDIM];    // bf16 42.0 MB (conv out; x-slice overwritten by gated v)
__device__ float g_dt[(size_t)NROWS * NHEADS];      // fp32  1.0 MB (raw dt, pre-bias)
__device__ float g_rowss[(size_t)NROWS * NHEADS];   // fp32  1.0 MB (per-row per-head sum of v^2)
__device__ short g_lstate[(size_t)BATCH * NHEADS * NCHUNK * HEADDIM * DSTATE]; // bf16 33.5 MB
__device__ float g_decayC[BATCH * NHEADS * NCHUNK];
__device__ short g_Winb[(size_t)ZSTR * DMODEL];     // bf16 W_in rows 0..1151
__device__ short g_Woutb[(size_t)DMODEL * DINNER];  // bf16 W_out * gnorm_w

__device__ __forceinline__ short f2bf(float f) {
    unsigned u = __float_as_uint(f);
    u += 0x7fff + ((u >> 16) & 1);
    return (short)(u >> 16);
}
__device__ __forceinline__ float bf2f(short s) {
    return __uint_as_float(((unsigned)(unsigned short)s) << 16);
}
// silu via single-instruction v_rcp_f32 (denom >= 1; ~1ulp rel err, far below bf16 rounding)
__device__ __forceinline__ float silu_fast(float s) {
    return s * __builtin_amdgcn_rcpf(1.f + __expf(-s));
}

__device__ __forceinline__ void stage16(const void* gsrc, void* ldst) {
    __builtin_amdgcn_global_load_lds(
        (const __attribute__((address_space(1))) void*)gsrc,
        (__attribute__((address_space(3))) void*)ldst, 16, 0, 0);
}

// element offset in a [64][64] bf16 tile with XOR chunk swizzle
__device__ __forceinline__ int swz(int row, int col) {
    return row * 64 + ((((col >> 3) ^ row) & 7) << 3) + (col & 7);
}

// ---------------- weight convert: fp32 -> bf16 ----------------
__global__ __launch_bounds__(256) void convert_bf16_kernel(const float* __restrict__ src,
                                                           short* __restrict__ dst,
                                                           int n_valid, int n_total) {
    const int i = blockIdx.x * 256 + threadIdx.x;
    if (i < n_total) dst[i] = (i < n_valid) ? f2bf(src[i]) : (short)0;
}

// ---------------- W_out convert with gnorm_w folded ----------------
__global__ __launch_bounds__(256) void convert_wout_kernel(const float* __restrict__ src,
                                                           const float* __restrict__ gw,
                                                           short* __restrict__ dst) {
    const int i = blockIdx.x * 256 + threadIdx.x;
    if (i < DMODEL * DINNER) dst[i] = f2bf(src[i] * gw[i % DINNER]);
}

// ---------------- rmsnorm of x (D=256) -> bf16 xn AND exact fp32 dt (8 heads) ----------
__global__ __launch_bounds__(256) void rmsnorm_dt_kernel(const float* __restrict__ x,
                                                         const float* __restrict__ w,
                                                         const float* __restrict__ W_in,
                                                         short* __restrict__ xn,
                                                         float* __restrict__ dt) {
    const int row  = blockIdx.x * 4 + (threadIdx.x >> 6);
    const int lane = threadIdx.x & 63;
    const float4 v = *(const float4*)(x + (size_t)row * DMODEL + lane * 4);
    float ss = v.x * v.x + v.y * v.y + v.z * v.z + v.w * v.w;
#pragma unroll
    for (int off = 1; off < 64; off <<= 1) ss += __shfl_xor(ss, off);
    const float rs = rsqrtf(ss * (1.0f / DMODEL) + 1.1920929e-7f);
    const float4 wv = *(const float4*)(w + lane * 4);
    const float4 xn4 = make_float4(v.x * rs * wv.x, v.y * rs * wv.y,
                                   v.z * rs * wv.z, v.w * rs * wv.w);
    short4 o;
    o.x = f2bf(xn4.x); o.y = f2bf(xn4.y); o.z = f2bf(xn4.z); o.w = f2bf(xn4.w);
    *(short4*)(xn + (size_t)row * DMODEL + lane * 4) = o;
#pragma unroll
    for (int h = 0; h < NHEADS; ++h) {
        const float4 ww = *(const float4*)(W_in + (size_t)(DPROJ - NHEADS + h) * DMODEL + lane * 4);
        float p = xn4.x * ww.x + xn4.y * ww.y + xn4.z * ww.z + xn4.w * ww.w;
#pragma unroll
        for (int off = 1; off < 64; off <<= 1) p += __shfl_xor(p, off);
        if (lane == 0) dt[(size_t)row * NHEADS + h] = p;
    }
}

// ---------------- bf16 MFMA GEMM: C[M][N] = A[M][K] * B[N][K]^T ----------
template <bool RES, typename OUT>
__global__ __launch_bounds__(256) void gemm_bf16_nt(const short* __restrict__ A,
                                                    const short* __restrict__ B,
                                                    const float* __restrict__ R,
                                                    const float* __restrict__ RS,
                                                    OUT* __restrict__ C,
                                                    int NX, int M, int N, int K, int LDA) {
    const int L   = blockIdx.x;
    const int xcd = L & 7;
    const int r   = L >> 3;
    const int mstrips_per_xcd = (M / 128) >> 3;
    const int mblk = xcd * mstrips_per_xcd + r / NX;
    const int nblk = r % NX;
    const int m0 = mblk * 128, n0 = nblk * 128;

    __shared__ __align__(16) short Asl[128 * 64];   // 16 KB
    __shared__ __align__(16) short Bsl[128 * 64];   // 16 KB
    const int tid  = threadIdx.x;
    const int lane = tid & 63;
    const int wid  = tid >> 6;
    const int wrow = (wid >> 1) * 64, wcol = (wid & 1) * 64;

    f32x4 acc[4][4];
#pragma unroll
    for (int m = 0; m < 4; ++m)
#pragma unroll
        for (int n = 0; n < 4; ++n) acc[m][n] = (f32x4)0.f;

    const int wbase = (tid & 0xC0) * 8;

    for (int k0 = 0; k0 < K; k0 += 64) {
#pragma unroll
        for (int rr = 0; rr < 4; ++rr) {
            const int idx = rr * 256 + tid;
            const int row = idx >> 3;
            const int cs  = idx & 7;
            const int ko  = (cs ^ (row & 7)) * 8;
            const int r6  = row & 63;
            const int brow = (row & 64) + (((r6 & 15) << 2) | (r6 >> 4));
            stage16(A + (size_t)(m0 + row) * LDA + k0 + ko, Asl + rr * 2048 + wbase);
            stage16(B + (size_t)(n0 + brow) * K + k0 + ko, Bsl + rr * 2048 + wbase);
        }
        __syncthreads();
#pragma unroll
        for (int ks = 0; ks < 2; ++ks) {
            bf16x8 af[4], bfr[4];
#pragma unroll
            for (int m = 0; m < 4; ++m) {
                const int arow = wrow + m * 16 + (lane & 15);
                const int ch = (ks * 4 + (lane >> 4)) ^ (arow & 7);
                af[m] = *(const bf16x8*)(Asl + arow * 64 + ch * 8);
            }
#pragma unroll
            for (int n = 0; n < 4; ++n) {
                const int brw = wcol + n * 16 + (lane & 15);
                const int ch = (ks * 4 + (lane >> 4)) ^ (brw & 7);
                bfr[n] = *(const bf16x8*)(Bsl + brw * 64 + ch * 8);
            }
#pragma unroll
            for (int m = 0; m < 4; ++m)
#pragma unroll
                for (int n = 0; n < 4; ++n)
                    acc[m][n] = __builtin_amdgcn_mfma_f32_16x16x32_bf16(af[m], bfr[n], acc[m][n], 0, 0, 0);
        }
        __syncthreads();
    }

    const int r0 = (lane >> 4) * 4;
    const int gcol = n0 + wcol + (lane & 15) * 4;
#pragma unroll
    for (int m = 0; m < 4; ++m) {
        const int grow = m0 + wrow + m * 16 + r0;
        if (gcol < N) {
#pragma unroll
            for (int reg = 0; reg < 4; ++reg) {
                if constexpr (sizeof(OUT) == 2) {
                    short4 o;
                    o.x = f2bf(acc[m][0][reg]); o.y = f2bf(acc[m][1][reg]);
                    o.z = f2bf(acc[m][2][reg]); o.w = f2bf(acc[m][3][reg]);
                    *(short4*)(C + (size_t)(grow + reg) * N + gcol) = o;
                } else {
                    f32x4 v;
                    v[0] = acc[m][0][reg]; v[1] = acc[m][1][reg];
                    v[2] = acc[m][2][reg]; v[3] = acc[m][3][reg];
                    if (RES) {
                        const float* rp = RS + (size_t)(grow + reg) * NHEADS;
                        const f32x4 s0 = *(const f32x4*)rp;
                        const f32x4 s1 = *(const f32x4*)(rp + 4);
                        const float sum = s0[0] + s0[1] + s0[2] + s0[3] +
                                          s1[0] + s1[1] + s1[2] + s1[3];
                        const float rsn = __builtin_amdgcn_rsqf(sum * (1.0f / DINNER) + 1e-5f);
                        v *= rsn;
                        v += *(const f32x4*)(R + (size_t)(grow + reg) * N + gcol);
                    }
                    *(f32x4*)(C + (size_t)(grow + reg) * N + gcol) = v;
                }
            }
        }
    }
}

// ---- depthwise causal conv(4) + bias + SiLU: sliding window, 8 rows x 8 ch per thread ----
__global__ __launch_bounds__(256) void conv_silu_kernel(const short* __restrict__ zxb,
                                                        const float* __restrict__ cw,
                                                        const float* __restrict__ cb,
                                                        short* __restrict__ xbc) {
    const int idx = blockIdx.x * 256 + threadIdx.x;   // over (NROWS/8)*80
    const int c8  = (idx % 80) * 8;
    const int bl0 = (idx / 80) * 8;                   // first of 8 rows
    const int l0  = bl0 & (SEQ - 1);
    const short* src = zxb + (size_t)bl0 * ZSTR + DINNER + c8;

    float4 w4[8];
    float bias[8];
#pragma unroll
    for (int j = 0; j < 8; ++j) w4[j] = *(const float4*)(cw + (c8 + j) * 4);
    {
        const float4 b0 = *(const float4*)(cb + c8);
        const float4 b1 = *(const float4*)(cb + c8 + 4);
        bias[0] = b0.x; bias[1] = b0.y; bias[2] = b0.z; bias[3] = b0.w;
        bias[4] = b1.x; bias[5] = b1.y; bias[6] = b1.z; bias[7] = b1.w;
    }

    bf16x8 rowv[11];                                  // rows l0-3 .. l0+7
#pragma unroll
    for (int m = 0; m < 11; ++m) {
        if (l0 + m - 3 >= 0)
            rowv[m] = *(const bf16x8*)(src + (ptrdiff_t)(m - 3) * ZSTR);
        else
            rowv[m] = (bf16x8)0;
    }

#pragma unroll
    for (int r = 0; r < 8; ++r) {
        float acc[8];
#pragma unroll
        for (int j = 0; j < 8; ++j) acc[j] = bias[j];
#pragma unroll
        for (int k = 0; k < 4; ++k) {
            const bf16x8 tap = rowv[r + k];
#pragma unroll
            for (int j = 0; j < 8; ++j)
                acc[j] = fmaf(bf2f(tap[j]), ((const float*)&w4[j])[k], acc[j]);
        }
        short8v o;
#pragma unroll
        for (int j = 0; j < 8; ++j)
            o[j] = f2bf(silu_fast(acc[j]));
        *(short8v*)(xbc + (size_t)(bl0 + r) * CONVDIM + c8) = o;
    }
}

// ---------------- scan pass 1 (MFMA): L[p][n] = sum_t X[t][p] * (w_t * B[t][n]) ----------
// Per-wave redundant prefix (no wsh LDS / extra barrier); w fetched via __shfl.
__global__ __launch_bounds__(256) void chunk_state_mfma(const float* __restrict__ dt,
                                                        const short* __restrict__ xbc,
                                                        const float* __restrict__ dt_bias,
                                                        const float* __restrict__ A_log,
                                                        short* __restrict__ lstate,
                                                        float* __restrict__ decayC) {
    const int bhc = blockIdx.x;
    const int c = bhc & (NCHUNK - 1), bh = bhc >> 6, h = bh & (NHEADS - 1), b = bh >> 3;
    const int tid = threadIdx.x, lane = tid & 63, wid = tid >> 6;
    __shared__ short XT[64 * LSTR];   // X^T, slot-permuted
    __shared__ short BT[64 * LSTR];   // (w*B)^T, slot-permuted
    const size_t row0 = (size_t)b * SEQ + (size_t)c * CHUNK;

    const float aneg  = -__expf(A_log[h]);
    const float dbias = dt_bias[h];
    const float draw = dt[(row0 + lane) * NHEADS + h] + dbias;
    const float dtv  = (draw > 20.f) ? draw : log1pf(__expf(draw));
    float cum = aneg * dtv;
#pragma unroll
    for (int off = 1; off < 64; off <<= 1) {
        const float nv = __shfl_up(cum, off);
        if (lane >= off) cum += nv;
    }
    const float total = __shfl(cum, 63);
    const float wval  = __expf(total - cum) * dtv;
    if (tid == 63) decayC[bhc] = __expf(total);

#pragma unroll
    for (int r = 0; r < 4; ++r) {
        const int idx  = tid + r * 256;
        const int trow = idx >> 4;
        const int q    = idx & 15;
        const int c4   = q * 4;
        const short* rp = xbc + (row0 + trow) * CONVDIM;
        const short4 xv = *(const short4*)(rp + h * 64 + c4);
        const short4 bv = *(const short4*)(rp + DINNER + c4);
        const float w = __shfl(wval, trow);
        XT[(0 * 16 + q) * LSTR + trow] = xv.x;
        XT[(1 * 16 + q) * LSTR + trow] = xv.y;
        XT[(2 * 16 + q) * LSTR + trow] = xv.z;
        XT[(3 * 16 + q) * LSTR + trow] = xv.w;
        BT[(0 * 16 + q) * LSTR + trow] = f2bf(bf2f(bv.x) * w);
        BT[(1 * 16 + q) * LSTR + trow] = f2bf(bf2f(bv.y) * w);
        BT[(2 * 16 + q) * LSTR + trow] = f2bf(bf2f(bv.z) * w);
        BT[(3 * 16 + q) * LSTR + trow] = f2bf(bf2f(bv.w) * w);
    }
    __syncthreads();

    f32x4 acc[4];
#pragma unroll
    for (int n = 0; n < 4; ++n) acc[n] = (f32x4)0.f;
#pragma unroll
    for (int ks = 0; ks < 2; ++ks) {
        const bf16x8 af = *(const bf16x8*)(XT + (wid * 16 + (lane & 15)) * LSTR + ks * 32 + (lane >> 4) * 8);
#pragma unroll
        for (int n = 0; n < 4; ++n) {
            const bf16x8 bfv = *(const bf16x8*)(BT + (n * 16 + (lane & 15)) * LSTR + ks * 32 + (lane >> 4) * 8);
            acc[n] = __builtin_amdgcn_mfma_f32_16x16x32_bf16(af, bfv, acc[n], 0, 0, 0);
        }
    }
    short* lp = lstate + ((size_t)bhc << 12);
    const int hi = lane >> 4;
    const int ncol = (lane & 15) * 4;
#pragma unroll
    for (int reg = 0; reg < 4; ++reg) {
        const int p = 16 * hi + 4 * reg + wid;
        short4 o;
        o.x = f2bf(acc[0][reg]); o.y = f2bf(acc[1][reg]);
        o.z = f2bf(acc[2][reg]); o.w = f2bf(acc[3][reg]);
        *(short4*)(lp + p * 64 + ncol) = o;
    }
}

// ---------------- scan pass 2: inter-chunk recurrence, short4-wide ----------
__global__ __launch_bounds__(256) void state_prefix_kernel(short* __restrict__ lstate,
                                                           const float* __restrict__ decayC) {
    const int idx = blockIdx.x * 256 + threadIdx.x;
    const int bh  = idx >> 10;
    const int pn4 = (idx & 1023) * 4;
    float S0 = 0.f, S1 = 0.f, S2 = 0.f, S3 = 0.f;
    for (int c = 0; c < NCHUNK; ++c) {
        short4* ptr = (short4*)(lstate + (((size_t)bh * NCHUNK + c) << 12) + pn4);
        const short4 l4 = *ptr;
        short4 o;
        o.x = f2bf(S0); o.y = f2bf(S1); o.z = f2bf(S2); o.w = f2bf(S3);
        *ptr = o;
        const float d = decayC[bh * NCHUNK + c];
        S0 = fmaf(S0, d, bf2f(l4.x));
        S1 = fmaf(S1, d, bf2f(l4.y));
        S2 = fmaf(S2, d, bf2f(l4.z));
        S3 = fmaf(S3, d, bf2f(l4.w));
    }
}

// ---- scan pass 3 (MFMA): y = mask(C@B^T)@X + exp(cum)*(C@SP^T) + Dp*X, fused gating.
// XOR-swizzled [64][64] tiles (no pad) -> LDS 32768 B. cums/dt in per-wave registers.
// Mask uses DIRECT exp(cum_s - cum_t) (arg <= 0, underflow-safe). SiLU via v_rcp. ----
__global__ __launch_bounds__(256) void chunk_scan_mfma(const float* __restrict__ dt,
                                                       short* __restrict__ xbc,
                                                       const short* __restrict__ zxb,
                                                       float* __restrict__ rowss,
                                                       const float* __restrict__ dt_bias,
                                                       const float* __restrict__ A_log,
                                                       const float* __restrict__ Dp,
                                                       const short* __restrict__ lstate) {
    const int bhc = blockIdx.x;
    const int c = bhc & (NCHUNK - 1), bh = bhc >> 6, h = bh & (NHEADS - 1), b = bh >> 3;
    const int tid = threadIdx.x, lane = tid & 63, wid = tid >> 6;
    __shared__ short BsMs[64 * 64]; // B rows [t][n]; later masked scores [s][t]
    __shared__ short Cs[64 * 64];   // C rows [s][n]
    __shared__ short XT[64 * 64];   // X^T, slot-permuted
    __shared__ short SP[64 * 64];   // prefix state, slot-permuted
    short* Bs = BsMs;
    short* Ms = BsMs;
    const size_t row0 = (size_t)b * SEQ + (size_t)c * CHUNK;

    // per-wave redundant fp32 prefix of aneg*dt (identical across waves)
    const float aneg  = -__expf(A_log[h]);
    const float dbias = dt_bias[h];
    const float draw = dt[(row0 + lane) * NHEADS + h] + dbias;
    const float dtv  = (draw > 20.f) ? draw : log1pf(__expf(draw));
    float cum = aneg * dtv;
#pragma unroll
    for (int off = 1; off < 64; off <<= 1) {
        const float nv = __shfl_up(cum, off);
        if (lane >= off) cum += nv;
    }

#pragma unroll
    for (int r = 0; r < 4; ++r) {
        const int idx  = tid + r * 256;
        const int trow = idx >> 4;
        const int q    = idx & 15;
        const int c4   = q * 4;
        const short* rp = xbc + (row0 + trow) * CONVDIM;
        const short4 xv = *(const short4*)(rp + h * 64 + c4);
        const int hoff = ((((q >> 1) ^ trow) & 7) << 3) + (q & 1) * 4;
        *(short4*)(Bs + trow * 64 + hoff) = *(const short4*)(rp + DINNER + c4);
        *(short4*)(Cs + trow * 64 + hoff) = *(const short4*)(rp + DINNER + DSTATE + c4);
        XT[swz(0 * 16 + q, trow)] = xv.x;
        XT[swz(1 * 16 + q, trow)] = xv.y;
        XT[swz(2 * 16 + q, trow)] = xv.z;
        XT[swz(3 * 16 + q, trow)] = xv.w;
    }
#pragma unroll
    for (int r = 0; r < 4; ++r) {
        const int idx = tid + r * 256;
        const int p = idx >> 4, q = idx & 15;
        const int pslot = ((p & 3) << 4) | (p >> 2);
        const int hoff = ((((q >> 1) ^ pslot) & 7) << 3) + (q & 1) * 4;
        *(short4*)(SP + pslot * 64 + hoff) =
            *(const short4*)(lstate + ((size_t)bhc << 12) + p * 64 + q * 4);
    }
    __syncthreads();

    // G = C @ B^T (over n)
    f32x4 accG[4];
#pragma unroll
    for (int tf = 0; tf < 4; ++tf) accG[tf] = (f32x4)0.f;
    __builtin_amdgcn_s_setprio(1);
#pragma unroll
    for (int ks = 0; ks < 2; ++ks) {
        const int crow = wid * 16 + (lane & 15);
        const bf16x8 af = *(const bf16x8*)(Cs + crow * 64 + (((ks * 4 + (lane >> 4)) ^ crow) & 7) * 8);
#pragma unroll
        for (int tf = 0; tf < 4; ++tf) {
            const int brw = tf * 16 + (lane & 15);
            const bf16x8 bfv = *(const bf16x8*)(Bs + brw * 64 + (((ks * 4 + (lane >> 4)) ^ brw) & 7) * 8);
            accG[tf] = __builtin_amdgcn_mfma_f32_16x16x32_bf16(af, bfv, accG[tf], 0, 0, 0);
        }
    }
    __builtin_amdgcn_s_setprio(0);
    __syncthreads();   // all waves done reading Bs before Ms overlays it

    // causal mask + decay scale -> Ms (bf16), overlaid on Bs
    const int srow0 = wid * 16 + (lane >> 4) * 4;
    float csr[4];
#pragma unroll
    for (int reg = 0; reg < 4; ++reg) csr[reg] = __shfl(cum, srow0 + reg);
#pragma unroll
    for (int tf = 0; tf < 4; ++tf) {
        const int t = tf * 16 + (lane & 15);
        const float ct  = __shfl(cum, t);
        const float dtt = __shfl(dtv, t);
#pragma unroll
        for (int reg = 0; reg < 4; ++reg) {
            const int s = srow0 + reg;
            const float m = (t <= s) ? accG[tf][reg] * __expf(csr[reg] - ct) * dtt : 0.f;
            Ms[swz(s, t)] = f2bf(m);
        }
    }
    __syncthreads();

    // Y1 = M @ X ; Y2 = C @ SP^T
    f32x4 acc1[4], acc2[4];
#pragma unroll
    for (int pf = 0; pf < 4; ++pf) { acc1[pf] = (f32x4)0.f; acc2[pf] = (f32x4)0.f; }
    __builtin_amdgcn_s_setprio(1);
#pragma unroll
    for (int ks = 0; ks < 2; ++ks) {
        const int mrow = wid * 16 + (lane & 15);
        const int ch = ks * 4 + (lane >> 4);
        const bf16x8 am = *(const bf16x8*)(Ms + mrow * 64 + ((ch ^ mrow) & 7) * 8);
        const bf16x8 ac = *(const bf16x8*)(Cs + mrow * 64 + ((ch ^ mrow) & 7) * 8);
#pragma unroll
        for (int pf = 0; pf < 4; ++pf) {
            const int prow = pf * 16 + (lane & 15);
            const bf16x8 bx = *(const bf16x8*)(XT + prow * 64 + ((ch ^ prow) & 7) * 8);
            const bf16x8 bs = *(const bf16x8*)(SP + prow * 64 + ((ch ^ prow) & 7) * 8);
            acc1[pf] = __builtin_amdgcn_mfma_f32_16x16x32_bf16(am, bx, acc1[pf], 0, 0, 0);
            acc2[pf] = __builtin_amdgcn_mfma_f32_16x16x32_bf16(ac, bs, acc2[pf], 0, 0, 0);
        }
    }
    __builtin_amdgcn_s_setprio(0);
    const float dpv = Dp[h];
    float es[4];
#pragma unroll
    for (int reg = 0; reg < 4; ++reg) es[reg] = __expf(csr[reg]);
    const int j = lane & 15;
#pragma unroll
    for (int reg = 0; reg < 4; ++reg) {
        const int s = srow0 + reg;
        const short4 z4 = *(const short4*)(zxb + (row0 + s) * ZSTR + h * 64 + j * 4);
        short4 o;
        float ssq = 0.f;
#pragma unroll
        for (int pf = 0; pf < 4; ++pf) {
            const float xv = bf2f(XT[swz(pf * 16 + j, s)]);
            const float yv = acc1[pf][reg] + es[reg] * acc2[pf][reg] + dpv * xv;
            const float v  = yv * silu_fast(bf2f(((const short*)&z4)[pf]));
            ((short*)&o)[pf] = f2bf(v);
            ssq = fmaf(v, v, ssq);
        }
        *(short4*)(xbc + (row0 + s) * CONVDIM + h * 64 + j * 4) = o;
        ssq += __shfl_xor(ssq, 1);
        ssq += __shfl_xor(ssq, 2);
        ssq += __shfl_xor(ssq, 4);
        ssq += __shfl_xor(ssq, 8);
        if (j == 0) rowss[(row0 + s) * NHEADS + h] = ssq;
    }
}

// ---------------- launch ----------------
extern "C" void kernel_launch(void* const* d_in, const int* in_sizes, int n_in,
                              void* d_out, int out_size, void* d_ws, size_t ws_size,
                              hipStream_t stream) {
    (void)in_sizes; (void)n_in; (void)out_size; (void)d_ws; (void)ws_size;
    const float* x      = (const float*)d_in[0];
    const float* W_in   = (const float*)d_in[1];
    const float* conv_w = (const float*)d_in[2];
    const float* conv_b = (const float*)d_in[3];
    const float* dt_b   = (const float*)d_in[4];
    const float* A_log  = (const float*)d_in[5];
    const float* Dp     = (const float*)d_in[6];
    const float* g_w    = (const float*)d_in[7];
    const float* n_w    = (const float*)d_in[8];
    const float* W_out  = (const float*)d_in[9];
    float* out = (float*)d_out;

    short *xn, *zxb, *xbc, *winb, *woutb, *lst;
    float *dtv, *dcy, *rss;
    hipGetSymbolAddress((void**)&xn,    HIP_SYMBOL(g_xn));
    hipGetSymbolAddress((void**)&zxb,   HIP_SYMBOL(g_zxb));
    hipGetSymbolAddress((void**)&xbc,   HIP_SYMBOL(g_xbc));
    hipGetSymbolAddress((void**)&dtv,   HIP_SYMBOL(g_dt));
    hipGetSymbolAddress((void**)&rss,   HIP_SYMBOL(g_rowss));
    hipGetSymbolAddress((void**)&lst,   HIP_SYMBOL(g_lstate));
    hipGetSymbolAddress((void**)&dcy,   HIP_SYMBOL(g_decayC));
    hipGetSymbolAddress((void**)&winb,  HIP_SYMBOL(g_Winb));
    hipGetSymbolAddress((void**)&woutb, HIP_SYMBOL(g_Woutb));

    convert_bf16_kernel<<<(ZSTR * DMODEL) / 256, 256, 0, stream>>>(
        W_in, winb, ZSTR * DMODEL, ZSTR * DMODEL);
    convert_wout_kernel<<<(DMODEL * DINNER) / 256, 256, 0, stream>>>(W_out, g_w, woutb);

    rmsnorm_dt_kernel<<<NROWS / 4, 256, 0, stream>>>(x, n_w, W_in, xn, dtv);

    gemm_bf16_nt<false, short><<<(ZSTR / 128) * (NROWS / 128), 256, 0, stream>>>(
        xn, winb, nullptr, nullptr, zxb, ZSTR / 128, NROWS, ZSTR, DMODEL, DMODEL);

    conv_silu_kernel<<<(NROWS / 8 * 80) / 256, 256, 0, stream>>>(zxb, conv_w, conv_b, xbc);

    chunk_state_mfma<<<BATCH * NHEADS * NCHUNK, 256, 0, stream>>>(dtv, xbc, dt_b, A_log, lst, dcy);
    state_prefix_kernel<<<(BATCH * NHEADS * HEADDIM * DSTATE) / (4 * 256), 256, 0, stream>>>(lst, dcy);
    chunk_scan_mfma<<<BATCH * NHEADS * NCHUNK, 256, 0, stream>>>(
        dtv, xbc, zxb, rss, dt_b, A_log, Dp, lst);

    gemm_bf16_nt<true, float><<<(DMODEL / 128) * (NROWS / 128), 256, 0, stream>>>(
        xbc, woutb, x, rss, out, DMODEL / 128, NROWS, DMODEL, DINNER, CONVDIM);
}

// Round 19
// 168.378 us; speedup vs baseline: 1.0950x; 1.0142x over previous
//
#include <hip/hip_runtime.h>
#include <math.h>

#define BATCH   8
#define SEQ     4096
#define DMODEL  256
#define DINNER  512
#define DSTATE  64
#define NHEADS  8
#define HEADDIM 64
#define CONVDIM 640          // DINNER + 2*DSTATE
#define DPROJ   1160         // full in-proj rows (for W_in/dt indexing)
#define ZSTR    1152         // z | xBC columns actually materialized (9*128)
#define NROWS   (BATCH*SEQ)  // 32768
#define CHUNK   64
#define NCHUNK  (SEQ/CHUNK)  // 64
#define LSTR    72           // LDS row stride for chunk_state (shorts)

typedef short bf16x8 __attribute__((ext_vector_type(8)));
typedef short short8v __attribute__((ext_vector_type(8)));
typedef float f32x4 __attribute__((ext_vector_type(4)));

// ---- static workspace (BSS) ----
__device__ short g_xn[(size_t)NROWS * DMODEL];      // bf16 16.8 MB
__device__ short g_zxb[(size_t)NROWS * ZSTR];       // bf16 75.5 MB (z | xBC)
__device__ short g_xbc[(size_t)NROWS * CONVDIM];    // bf16 42.0 MB (conv out; x-slice overwritten by gated v)
__device__ float g_dt[(size_t)NROWS * NHEADS];      // fp32  1.0 MB (raw dt, pre-bias)
__device__ float g_rowss[(size_t)NROWS * NHEADS];   // fp32  1.0 MB (per-row per-head sum of v^2)
__device__ short g_lstate[(size_t)BATCH * NHEADS * NCHUNK * HEADDIM * DSTATE]; // bf16 33.5 MB
__device__ float g_decayC[BATCH * NHEADS * NCHUNK];
__device__ short g_Winb[(size_t)ZSTR * DMODEL];     // bf16 W_in rows 0..1151
__device__ short g_Woutb[(size_t)DMODEL * DINNER];  // bf16 W_out * gnorm_w

__device__ __forceinline__ short f2bf(float f) {
    unsigned u = __float_as_uint(f);
    u += 0x7fff + ((u >> 16) & 1);
    return (short)(u >> 16);
}
__device__ __forceinline__ float bf2f(short s) {
    return __uint_as_float(((unsigned)(unsigned short)s) << 16);
}
// silu via single-instruction v_rcp_f32 (denom >= 1; ~1ulp rel err, far below bf16 rounding)
__device__ __forceinline__ float silu_fast(float s) {
    return s * __builtin_amdgcn_rcpf(1.f + __expf(-s));
}

__device__ __forceinline__ void stage16(const void* gsrc, void* ldst) {
    __builtin_amdgcn_global_load_lds(
        (const __attribute__((address_space(1))) void*)gsrc,
        (__attribute__((address_space(3))) void*)ldst, 16, 0, 0);
}

// element offset in a [64][64] bf16 tile with XOR chunk swizzle
__device__ __forceinline__ int swz(int row, int col) {
    return row * 64 + ((((col >> 3) ^ row) & 7) << 3) + (col & 7);
}

// ---------------- merged weight convert: W_in -> bf16, W_out*gnorm_w -> bf16 ----------
__global__ __launch_bounds__(256) void convert_weights_kernel(const float* __restrict__ W_in,
                                                              const float* __restrict__ W_out,
                                                              const float* __restrict__ gw,
                                                              short* __restrict__ winb,
                                                              short* __restrict__ woutb) {
    const int i = blockIdx.x * 256 + threadIdx.x;
    if (i < ZSTR * DMODEL)    winb[i]  = f2bf(W_in[i]);
    if (i < DMODEL * DINNER)  woutb[i] = f2bf(W_out[i] * gw[i % DINNER]);
}

// ---------------- rmsnorm of x (D=256) -> bf16 xn AND exact fp32 dt (8 heads) ----------
__global__ __launch_bounds__(256) void rmsnorm_dt_kernel(const float* __restrict__ x,
                                                         const float* __restrict__ w,
                                                         const float* __restrict__ W_in,
                                                         short* __restrict__ xn,
                                                         float* __restrict__ dt) {
    const int row  = blockIdx.x * 4 + (threadIdx.x >> 6);
    const int lane = threadIdx.x & 63;
    const float4 v = *(const float4*)(x + (size_t)row * DMODEL + lane * 4);
    float ss = v.x * v.x + v.y * v.y + v.z * v.z + v.w * v.w;
#pragma unroll
    for (int off = 1; off < 64; off <<= 1) ss += __shfl_xor(ss, off);
    const float rs = rsqrtf(ss * (1.0f / DMODEL) + 1.1920929e-7f);
    const float4 wv = *(const float4*)(w + lane * 4);
    const float4 xn4 = make_float4(v.x * rs * wv.x, v.y * rs * wv.y,
                                   v.z * rs * wv.z, v.w * rs * wv.w);
    short4 o;
    o.x = f2bf(xn4.x); o.y = f2bf(xn4.y); o.z = f2bf(xn4.z); o.w = f2bf(xn4.w);
    *(short4*)(xn + (size_t)row * DMODEL + lane * 4) = o;
#pragma unroll
    for (int h = 0; h < NHEADS; ++h) {
        const float4 ww = *(const float4*)(W_in + (size_t)(DPROJ - NHEADS + h) * DMODEL + lane * 4);
        float p = xn4.x * ww.x + xn4.y * ww.y + xn4.z * ww.z + xn4.w * ww.w;
#pragma unroll
        for (int off = 1; off < 64; off <<= 1) p += __shfl_xor(p, off);
        if (lane == 0) dt[(size_t)row * NHEADS + h] = p;
    }
}

// ---------------- bf16 MFMA GEMM: C[M][N] = A[M][K] * B[N][K]^T ----------
template <bool RES, typename OUT>
__global__ __launch_bounds__(256) void gemm_bf16_nt(const short* __restrict__ A,
                                                    const short* __restrict__ B,
                                                    const float* __restrict__ R,
                                                    const float* __restrict__ RS,
                                                    OUT* __restrict__ C,
                                                    int NX, int M, int N, int K, int LDA) {
    const int L   = blockIdx.x;
    const int xcd = L & 7;
    const int r   = L >> 3;
    const int mstrips_per_xcd = (M / 128) >> 3;
    const int mblk = xcd * mstrips_per_xcd + r / NX;
    const int nblk = r % NX;
    const int m0 = mblk * 128, n0 = nblk * 128;

    __shared__ __align__(16) short Asl[128 * 64];   // 16 KB
    __shared__ __align__(16) short Bsl[128 * 64];   // 16 KB
    const int tid  = threadIdx.x;
    const int lane = tid & 63;
    const int wid  = tid >> 6;
    const int wrow = (wid >> 1) * 64, wcol = (wid & 1) * 64;

    f32x4 acc[4][4];
#pragma unroll
    for (int m = 0; m < 4; ++m)
#pragma unroll
        for (int n = 0; n < 4; ++n) acc[m][n] = (f32x4)0.f;

    const int wbase = (tid & 0xC0) * 8;

    for (int k0 = 0; k0 < K; k0 += 64) {
#pragma unroll
        for (int rr = 0; rr < 4; ++rr) {
            const int idx = rr * 256 + tid;
            const int row = idx >> 3;
            const int cs  = idx & 7;
            const int ko  = (cs ^ (row & 7)) * 8;
            const int r6  = row & 63;
            const int brow = (row & 64) + (((r6 & 15) << 2) | (r6 >> 4));
            stage16(A + (size_t)(m0 + row) * LDA + k0 + ko, Asl + rr * 2048 + wbase);
            stage16(B + (size_t)(n0 + brow) * K + k0 + ko, Bsl + rr * 2048 + wbase);
        }
        __syncthreads();
#pragma unroll
        for (int ks = 0; ks < 2; ++ks) {
            bf16x8 af[4], bfr[4];
#pragma unroll
            for (int m = 0; m < 4; ++m) {
                const int arow = wrow + m * 16 + (lane & 15);
                const int ch = (ks * 4 + (lane >> 4)) ^ (arow & 7);
                af[m] = *(const bf16x8*)(Asl + arow * 64 + ch * 8);
            }
#pragma unroll
            for (int n = 0; n < 4; ++n) {
                const int brw = wcol + n * 16 + (lane & 15);
                const int ch = (ks * 4 + (lane >> 4)) ^ (brw & 7);
                bfr[n] = *(const bf16x8*)(Bsl + brw * 64 + ch * 8);
            }
#pragma unroll
            for (int m = 0; m < 4; ++m)
#pragma unroll
                for (int n = 0; n < 4; ++n)
                    acc[m][n] = __builtin_amdgcn_mfma_f32_16x16x32_bf16(af[m], bfr[n], acc[m][n], 0, 0, 0);
        }
        __syncthreads();
    }

    const int r0 = (lane >> 4) * 4;
    const int gcol = n0 + wcol + (lane & 15) * 4;
#pragma unroll
    for (int m = 0; m < 4; ++m) {
        const int grow = m0 + wrow + m * 16 + r0;
        if (gcol < N) {
#pragma unroll
            for (int reg = 0; reg < 4; ++reg) {
                if constexpr (sizeof(OUT) == 2) {
                    short4 o;
                    o.x = f2bf(acc[m][0][reg]); o.y = f2bf(acc[m][1][reg]);
                    o.z = f2bf(acc[m][2][reg]); o.w = f2bf(acc[m][3][reg]);
                    *(short4*)(C + (size_t)(grow + reg) * N + gcol) = o;
                } else {
                    f32x4 v;
                    v[0] = acc[m][0][reg]; v[1] = acc[m][1][reg];
                    v[2] = acc[m][2][reg]; v[3] = acc[m][3][reg];
                    if (RES) {
                        const float* rp = RS + (size_t)(grow + reg) * NHEADS;
                        const f32x4 s0 = *(const f32x4*)rp;
                        const f32x4 s1 = *(const f32x4*)(rp + 4);
                        const float sum = s0[0] + s0[1] + s0[2] + s0[3] +
                                          s1[0] + s1[1] + s1[2] + s1[3];
                        const float rsn = __builtin_amdgcn_rsqf(sum * (1.0f / DINNER) + 1e-5f);
                        v *= rsn;
                        v += *(const f32x4*)(R + (size_t)(grow + reg) * N + gcol);
                    }
                    *(f32x4*)(C + (size_t)(grow + reg) * N + gcol) = v;
                }
            }
        }
    }
}

// ---- depthwise causal conv(4) + bias + SiLU: sliding window, 8 rows x 8 ch per thread ----
__global__ __launch_bounds__(256) void conv_silu_kernel(const short* __restrict__ zxb,
                                                        const float* __restrict__ cw,
                                                        const float* __restrict__ cb,
                                                        short* __restrict__ xbc) {
    const int idx = blockIdx.x * 256 + threadIdx.x;   // over (NROWS/8)*80
    const int c8  = (idx % 80) * 8;
    const int bl0 = (idx / 80) * 8;                   // first of 8 rows
    const int l0  = bl0 & (SEQ - 1);
    const short* src = zxb + (size_t)bl0 * ZSTR + DINNER + c8;

    float4 w4[8];
    float bias[8];
#pragma unroll
    for (int j = 0; j < 8; ++j) w4[j] = *(const float4*)(cw + (c8 + j) * 4);
    {
        const float4 b0 = *(const float4*)(cb + c8);
        const float4 b1 = *(const float4*)(cb + c8 + 4);
        bias[0] = b0.x; bias[1] = b0.y; bias[2] = b0.z; bias[3] = b0.w;
        bias[4] = b1.x; bias[5] = b1.y; bias[6] = b1.z; bias[7] = b1.w;
    }

    bf16x8 rowv[11];                                  // rows l0-3 .. l0+7
#pragma unroll
    for (int m = 0; m < 11; ++m) {
        if (l0 + m - 3 >= 0)
            rowv[m] = *(const bf16x8*)(src + (ptrdiff_t)(m - 3) * ZSTR);
        else
            rowv[m] = (bf16x8)0;
    }

#pragma unroll
    for (int r = 0; r < 8; ++r) {
        float acc[8];
#pragma unroll
        for (int j = 0; j < 8; ++j) acc[j] = bias[j];
#pragma unroll
        for (int k = 0; k < 4; ++k) {
            const bf16x8 tap = rowv[r + k];
#pragma unroll
            for (int j = 0; j < 8; ++j)
                acc[j] = fmaf(bf2f(tap[j]), ((const float*)&w4[j])[k], acc[j]);
        }
        short8v o;
#pragma unroll
        for (int j = 0; j < 8; ++j)
            o[j] = f2bf(silu_fast(acc[j]));
        *(short8v*)(xbc + (size_t)(bl0 + r) * CONVDIM + c8) = o;
    }
}

// ---------------- scan pass 1 (MFMA): L[p][n] = sum_t X[t][p] * (w_t * B[t][n]) ----------
__global__ __launch_bounds__(256) void chunk_state_mfma(const float* __restrict__ dt,
                                                        const short* __restrict__ xbc,
                                                        const float* __restrict__ dt_bias,
                                                        const float* __restrict__ A_log,
                                                        short* __restrict__ lstate,
                                                        float* __restrict__ decayC) {
    const int bhc = blockIdx.x;
    const int c = bhc & (NCHUNK - 1), bh = bhc >> 6, h = bh & (NHEADS - 1), b = bh >> 3;
    const int tid = threadIdx.x, lane = tid & 63, wid = tid >> 6;
    __shared__ short XT[64 * LSTR];   // X^T, slot-permuted
    __shared__ short BT[64 * LSTR];   // (w*B)^T, slot-permuted
    const size_t row0 = (size_t)b * SEQ + (size_t)c * CHUNK;

    const float aneg  = -__expf(A_log[h]);
    const float dbias = dt_bias[h];
    const float draw = dt[(row0 + lane) * NHEADS + h] + dbias;
    const float dtv  = (draw > 20.f) ? draw : log1pf(__expf(draw));
    float cum = aneg * dtv;
#pragma unroll
    for (int off = 1; off < 64; off <<= 1) {
        const float nv = __shfl_up(cum, off);
        if (lane >= off) cum += nv;
    }
    const float total = __shfl(cum, 63);
    const float wval  = __expf(total - cum) * dtv;
    if (tid == 63) decayC[bhc] = __expf(total);

#pragma unroll
    for (int r = 0; r < 4; ++r) {
        const int idx  = tid + r * 256;
        const int trow = idx >> 4;
        const int q    = idx & 15;
        const int c4   = q * 4;
        const short* rp = xbc + (row0 + trow) * CONVDIM;
        const short4 xv = *(const short4*)(rp + h * 64 + c4);
        const short4 bv = *(const short4*)(rp + DINNER + c4);
        const float w = __shfl(wval, trow);
        XT[(0 * 16 + q) * LSTR + trow] = xv.x;
        XT[(1 * 16 + q) * LSTR + trow] = xv.y;
        XT[(2 * 16 + q) * LSTR + trow] = xv.z;
        XT[(3 * 16 + q) * LSTR + trow] = xv.w;
        BT[(0 * 16 + q) * LSTR + trow] = f2bf(bf2f(bv.x) * w);
        BT[(1 * 16 + q) * LSTR + trow] = f2bf(bf2f(bv.y) * w);
        BT[(2 * 16 + q) * LSTR + trow] = f2bf(bf2f(bv.z) * w);
        BT[(3 * 16 + q) * LSTR + trow] = f2bf(bf2f(bv.w) * w);
    }
    __syncthreads();

    f32x4 acc[4];
#pragma unroll
    for (int n = 0; n < 4; ++n) acc[n] = (f32x4)0.f;
#pragma unroll
    for (int ks = 0; ks < 2; ++ks) {
        const bf16x8 af = *(const bf16x8*)(XT + (wid * 16 + (lane & 15)) * LSTR + ks * 32 + (lane >> 4) * 8);
#pragma unroll
        for (int n = 0; n < 4; ++n) {
            const bf16x8 bfv = *(const bf16x8*)(BT + (n * 16 + (lane & 15)) * LSTR + ks * 32 + (lane >> 4) * 8);
            acc[n] = __builtin_amdgcn_mfma_f32_16x16x32_bf16(af, bfv, acc[n], 0, 0, 0);
        }
    }
    short* lp = lstate + ((size_t)bhc << 12);
    const int hi = lane >> 4;
    const int ncol = (lane & 15) * 4;
#pragma unroll
    for (int reg = 0; reg < 4; ++reg) {
        const int p = 16 * hi + 4 * reg + wid;
        short4 o;
        o.x = f2bf(acc[0][reg]); o.y = f2bf(acc[1][reg]);
        o.z = f2bf(acc[2][reg]); o.w = f2bf(acc[3][reg]);
        *(short4*)(lp + p * 64 + ncol) = o;
    }
}

// ---------------- scan pass 2: inter-chunk recurrence, short4-wide ----------
__global__ __launch_bounds__(256) void state_prefix_kernel(short* __restrict__ lstate,
                                                           const float* __restrict__ decayC) {
    const int idx = blockIdx.x * 256 + threadIdx.x;
    const int bh  = idx >> 10;
    const int pn4 = (idx & 1023) * 4;
    float S0 = 0.f, S1 = 0.f, S2 = 0.f, S3 = 0.f;
    for (int c = 0; c < NCHUNK; ++c) {
        short4* ptr = (short4*)(lstate + (((size_t)bh * NCHUNK + c) << 12) + pn4);
        const short4 l4 = *ptr;
        short4 o;
        o.x = f2bf(S0); o.y = f2bf(S1); o.z = f2bf(S2); o.w = f2bf(S3);
        *ptr = o;
        const float d = decayC[bh * NCHUNK + c];
        S0 = fmaf(S0, d, bf2f(l4.x));
        S1 = fmaf(S1, d, bf2f(l4.y));
        S2 = fmaf(S2, d, bf2f(l4.z));
        S3 = fmaf(S3, d, bf2f(l4.w));
    }
}

// ---- scan pass 3 (MFMA): y = mask(C@B^T)@X + exp(cum)*(C@SP^T) + Dp*X, fused gating.
// Mask decay: adaptive factored exp. Shift by chunk max cum0: E_s = exp(cum_s-cum0)<=1,
// D_t = dt*exp(cum0-cum_t) <= dt*e^range — safe iff range < 80 (wave-uniform branch);
// else exact per-entry exp (r18 path). ----
__global__ __launch_bounds__(256) void chunk_scan_mfma(const float* __restrict__ dt,
                                                       short* __restrict__ xbc,
                                                       const short* __restrict__ zxb,
                                                       float* __restrict__ rowss,
                                                       const float* __restrict__ dt_bias,
                                                       const float* __restrict__ A_log,
                                                       const float* __restrict__ Dp,
                                                       const short* __restrict__ lstate) {
    const int bhc = blockIdx.x;
    const int c = bhc & (NCHUNK - 1), bh = bhc >> 6, h = bh & (NHEADS - 1), b = bh >> 3;
    const int tid = threadIdx.x, lane = tid & 63, wid = tid >> 6;
    __shared__ short BsMs[64 * 64]; // B rows [t][n]; later masked scores [s][t]
    __shared__ short Cs[64 * 64];   // C rows [s][n]
    __shared__ short XT[64 * 64];   // X^T, slot-permuted
    __shared__ short SP[64 * 64];   // prefix state, slot-permuted
    short* Bs = BsMs;
    short* Ms = BsMs;
    const size_t row0 = (size_t)b * SEQ + (size_t)c * CHUNK;

    // per-wave redundant fp32 prefix of aneg*dt (identical across waves)
    const float aneg  = -__expf(A_log[h]);
    const float dbias = dt_bias[h];
    const float draw = dt[(row0 + lane) * NHEADS + h] + dbias;
    const float dtv  = (draw > 20.f) ? draw : log1pf(__expf(draw));
    float cum = aneg * dtv;
#pragma unroll
    for (int off = 1; off < 64; off <<= 1) {
        const float nv = __shfl_up(cum, off);
        if (lane >= off) cum += nv;
    }
    const float cum0  = __shfl(cum, 0);                 // chunk max (cum decreasing)
    const float range = cum0 - __shfl(cum, 63);         // >= 0
    const bool  fast  = (range < 80.f);                 // wave-uniform
    float Efac = 0.f, Dfac = 0.f;
    if (fast) {
        Efac = __expf(cum - cum0);                      // <= 1, > e^-80 (no underflow)
        Dfac = dtv * __expf(cum0 - cum);                // <= dt * e^80 (finite)
    }

#pragma unroll
    for (int r = 0; r < 4; ++r) {
        const int idx  = tid + r * 256;
        const int trow = idx >> 4;
        const int q    = idx & 15;
        const int c4   = q * 4;
        const short* rp = xbc + (row0 + trow) * CONVDIM;
        const short4 xv = *(const short4*)(rp + h * 64 + c4);
        const int hoff = ((((q >> 1) ^ trow) & 7) << 3) + (q & 1) * 4;
        *(short4*)(Bs + trow * 64 + hoff) = *(const short4*)(rp + DINNER + c4);
        *(short4*)(Cs + trow * 64 + hoff) = *(const short4*)(rp + DINNER + DSTATE + c4);
        XT[swz(0 * 16 + q, trow)] = xv.x;
        XT[swz(1 * 16 + q, trow)] = xv.y;
        XT[swz(2 * 16 + q, trow)] = xv.z;
        XT[swz(3 * 16 + q, trow)] = xv.w;
    }
#pragma unroll
    for (int r = 0; r < 4; ++r) {
        const int idx = tid + r * 256;
        const int p = idx >> 4, q = idx & 15;
        const int pslot = ((p & 3) << 4) | (p >> 2);
        const int hoff = ((((q >> 1) ^ pslot) & 7) << 3) + (q & 1) * 4;
        *(short4*)(SP + pslot * 64 + hoff) =
            *(const short4*)(lstate + ((size_t)bhc << 12) + p * 64 + q * 4);
    }
    __syncthreads();

    // G = C @ B^T (over n)
    f32x4 accG[4];
#pragma unroll
    for (int tf = 0; tf < 4; ++tf) accG[tf] = (f32x4)0.f;
    __builtin_amdgcn_s_setprio(1);
#pragma unroll
    for (int ks = 0; ks < 2; ++ks) {
        const int crow = wid * 16 + (lane & 15);
        const bf16x8 af = *(const bf16x8*)(Cs + crow * 64 + (((ks * 4 + (lane >> 4)) ^ crow) & 7) * 8);
#pragma unroll
        for (int tf = 0; tf < 4; ++tf) {
            const int brw = tf * 16 + (lane & 15);
            const bf16x8 bfv = *(const bf16x8*)(Bs + brw * 64 + (((ks * 4 + (lane >> 4)) ^ brw) & 7) * 8);
            accG[tf] = __builtin_amdgcn_mfma_f32_16x16x32_bf16(af, bfv, accG[tf], 0, 0, 0);
        }
    }
    __builtin_amdgcn_s_setprio(0);
    __syncthreads();   // all waves done reading Bs before Ms overlays it

    // causal mask + decay scale -> Ms (bf16), overlaid on Bs
    const int srow0 = wid * 16 + (lane >> 4) * 4;
    float csr[4];
#pragma unroll
    for (int reg = 0; reg < 4; ++reg) csr[reg] = __shfl(cum, srow0 + reg);
    if (fast) {
        float esh[4];
#pragma unroll
        for (int reg = 0; reg < 4; ++reg) esh[reg] = __shfl(Efac, srow0 + reg);
#pragma unroll
        for (int tf = 0; tf < 4; ++tf) {
            const int t = tf * 16 + (lane & 15);
            const float Dt = __shfl(Dfac, t);
#pragma unroll
            for (int reg = 0; reg < 4; ++reg) {
                const int s = srow0 + reg;
                const float m = (t <= s) ? accG[tf][reg] * esh[reg] * Dt : 0.f;
                Ms[swz(s, t)] = f2bf(m);
            }
        }
    } else {
#pragma unroll
        for (int tf = 0; tf < 4; ++tf) {
            const int t = tf * 16 + (lane & 15);
            const float ct  = __shfl(cum, t);
            const float dtt = __shfl(dtv, t);
#pragma unroll
            for (int reg = 0; reg < 4; ++reg) {
                const int s = srow0 + reg;
                const float m = (t <= s) ? accG[tf][reg] * __expf(csr[reg] - ct) * dtt : 0.f;
                Ms[swz(s, t)] = f2bf(m);
            }
        }
    }
    __syncthreads();

    // Y1 = M @ X ; Y2 = C @ SP^T
    f32x4 acc1[4], acc2[4];
#pragma unroll
    for (int pf = 0; pf < 4; ++pf) { acc1[pf] = (f32x4)0.f; acc2[pf] = (f32x4)0.f; }
    __builtin_amdgcn_s_setprio(1);
#pragma unroll
    for (int ks = 0; ks < 2; ++ks) {
        const int mrow = wid * 16 + (lane & 15);
        const int ch = ks * 4 + (lane >> 4);
        const bf16x8 am = *(const bf16x8*)(Ms + mrow * 64 + ((ch ^ mrow) & 7) * 8);
        const bf16x8 ac = *(const bf16x8*)(Cs + mrow * 64 + ((ch ^ mrow) & 7) * 8);
#pragma unroll
        for (int pf = 0; pf < 4; ++pf) {
            const int prow = pf * 16 + (lane & 15);
            const bf16x8 bx = *(const bf16x8*)(XT + prow * 64 + ((ch ^ prow) & 7) * 8);
            const bf16x8 bs = *(const bf16x8*)(SP + prow * 64 + ((ch ^ prow) & 7) * 8);
            acc1[pf] = __builtin_amdgcn_mfma_f32_16x16x32_bf16(am, bx, acc1[pf], 0, 0, 0);
            acc2[pf] = __builtin_amdgcn_mfma_f32_16x16x32_bf16(ac, bs, acc2[pf], 0, 0, 0);
        }
    }
    __builtin_amdgcn_s_setprio(0);
    const float dpv = Dp[h];
    float es[4];
#pragma unroll
    for (int reg = 0; reg < 4; ++reg) es[reg] = __expf(csr[reg]);
    const int j = lane & 15;
#pragma unroll
    for (int reg = 0; reg < 4; ++reg) {
        const int s = srow0 + reg;
        const short4 z4 = *(const short4*)(zxb + (row0 + s) * ZSTR + h * 64 + j * 4);
        short4 o;
        float ssq = 0.f;
#pragma unroll
        for (int pf = 0; pf < 4; ++pf) {
            const float xv = bf2f(XT[swz(pf * 16 + j, s)]);
            const float yv = acc1[pf][reg] + es[reg] * acc2[pf][reg] + dpv * xv;
            const float v  = yv * silu_fast(bf2f(((const short*)&z4)[pf]));
            ((short*)&o)[pf] = f2bf(v);
            ssq = fmaf(v, v, ssq);
        }
        *(short4*)(xbc + (row0 + s) * CONVDIM + h * 64 + j * 4) = o;
        ssq += __shfl_xor(ssq, 1);
        ssq += __shfl_xor(ssq, 2);
        ssq += __shfl_xor(ssq, 4);
        ssq += __shfl_xor(ssq, 8);
        if (j == 0) rowss[(row0 + s) * NHEADS + h] = ssq;
    }
}

// ---------------- launch ----------------
extern "C" void kernel_launch(void* const* d_in, const int* in_sizes, int n_in,
                              void* d_out, int out_size, void* d_ws, size_t ws_size,
                              hipStream_t stream) {
    (void)in_sizes; (void)n_in; (void)out_size; (void)d_ws; (void)ws_size;
    const float* x      = (const float*)d_in[0];
    const float* W_in   = (const float*)d_in[1];
    const float* conv_w = (const float*)d_in[2];
    const float* conv_b = (const float*)d_in[3];
    const float* dt_b   = (const float*)d_in[4];
    const float* A_log  = (const float*)d_in[5];
    const float* Dp     = (const float*)d_in[6];
    const float* g_w    = (const float*)d_in[7];
    const float* n_w    = (const float*)d_in[8];
    const float* W_out  = (const float*)d_in[9];
    float* out = (float*)d_out;

    short *xn, *zxb, *xbc, *winb, *woutb, *lst;
    float *dtv, *dcy, *rss;
    hipGetSymbolAddress((void**)&xn,    HIP_SYMBOL(g_xn));
    hipGetSymbolAddress((void**)&zxb,   HIP_SYMBOL(g_zxb));
    hipGetSymbolAddress((void**)&xbc,   HIP_SYMBOL(g_xbc));
    hipGetSymbolAddress((void**)&dtv,   HIP_SYMBOL(g_dt));
    hipGetSymbolAddress((void**)&rss,   HIP_SYMBOL(g_rowss));
    hipGetSymbolAddress((void**)&lst,   HIP_SYMBOL(g_lstate));
    hipGetSymbolAddress((void**)&dcy,   HIP_SYMBOL(g_decayC));
    hipGetSymbolAddress((void**)&winb,  HIP_SYMBOL(g_Winb));
    hipGetSymbolAddress((void**)&woutb, HIP_SYMBOL(g_Woutb));

    convert_weights_kernel<<<(ZSTR * DMODEL) / 256, 256, 0, stream>>>(
        W_in, W_out, g_w, winb, woutb);

    rmsnorm_dt_kernel<<<NROWS / 4, 256, 0, stream>>>(x, n_w, W_in, xn, dtv);

    gemm_bf16_nt<false, short><<<(ZSTR / 128) * (NROWS / 128), 256, 0, stream>>>(
        xn, winb, nullptr, nullptr, zxb, ZSTR / 128, NROWS, ZSTR, DMODEL, DMODEL);

    conv_silu_kernel<<<(NROWS / 8 * 80) / 256, 256, 0, stream>>>(zxb, conv_w, conv_b, xbc);

    chunk_state_mfma<<<BATCH * NHEADS * NCHUNK, 256, 0, stream>>>(dtv, xbc, dt_b, A_log, lst, dcy);
    state_prefix_kernel<<<(BATCH * NHEADS * HEADDIM * DSTATE) / (4 * 256), 256, 0, stream>>>(lst, dcy);
    chunk_scan_mfma<<<BATCH * NHEADS * NCHUNK, 256, 0, stream>>>(
        dtv, xbc, zxb, rss, dt_b, A_log, Dp, lst);

    gemm_bf16_nt<true, float><<<(DMODEL / 128) * (NROWS / 128), 256, 0, stream>>>(
        xbc, woutb, x, rss, out, DMODEL / 128, NROWS, DMODEL, DINNER, CONVDIM);
}

// Round 21
// 167.979 us; speedup vs baseline: 1.0976x; 1.0024x over previous
//
#include <hip/hip_runtime.h>
#include <math.h>

#define BATCH   8
#define SEQ     4096
#define DMODEL  256
#define DINNER  512
#define DSTATE  64
#define NHEADS  8
#define HEADDIM 64
#define CONVDIM 640          // DINNER + 2*DSTATE
#define DPROJ   1160         // full in-proj rows (for W_in/dt indexing)
#define ZSTR    1152         // z | xBC columns actually materialized (9*128)
#define NROWS   (BATCH*SEQ)  // 32768
#define CHUNK   64
#define NCHUNK  (SEQ/CHUNK)  // 64
#define LSTR    72           // LDS row stride for chunk_state (shorts)

typedef short bf16x8 __attribute__((ext_vector_type(8)));
typedef short short8v __attribute__((ext_vector_type(8)));
typedef float f32x4 __attribute__((ext_vector_type(4)));

// ---- static workspace (BSS) ----
__device__ short g_xn[(size_t)NROWS * DMODEL];      // bf16 16.8 MB
__device__ short g_zxb[(size_t)NROWS * ZSTR];       // bf16 75.5 MB (z | xBC)
__device__ short g_xbc[(size_t)NROWS * CONVDIM];    // bf16 42.0 MB (conv out; x-slice overwritten by gated v)
__device__ float g_dt[(size_t)NROWS * NHEADS];      // fp32  1.0 MB (raw dt, pre-bias)
__device__ float g_rowss[(size_t)NROWS * NHEADS];   // fp32  1.0 MB (per-row per-head sum of v^2)
__device__ short g_lstate[(size_t)BATCH * NHEADS * NCHUNK * HEADDIM * DSTATE]; // bf16 33.5 MB
__device__ float g_decayC[BATCH * NHEADS * NCHUNK];
__device__ short g_Winb[(size_t)ZSTR * DMODEL];     // bf16 W_in rows 0..1151
__device__ short g_Woutb[(size_t)DMODEL * DINNER];  // bf16 W_out * gnorm_w

__device__ __forceinline__ short f2bf(float f) {
    unsigned u = __float_as_uint(f);
    u += 0x7fff + ((u >> 16) & 1);
    return (short)(u >> 16);
}
__device__ __forceinline__ float bf2f(short s) {
    return __uint_as_float(((unsigned)(unsigned short)s) << 16);
}
// silu via single-instruction v_rcp_f32 (denom >= 1; ~1ulp rel err, far below bf16 rounding)
__device__ __forceinline__ float silu_fast(float s) {
    return s * __builtin_amdgcn_rcpf(1.f + __expf(-s));
}

__device__ __forceinline__ void stage16(const void* gsrc, void* ldst) {
    __builtin_amdgcn_global_load_lds(
        (const __attribute__((address_space(1))) void*)gsrc,
        (__attribute__((address_space(3))) void*)ldst, 16, 0, 0);
}

// element offset in a [64][64] bf16 tile with XOR chunk swizzle
__device__ __forceinline__ int swz(int row, int col) {
    return row * 64 + ((((col >> 3) ^ row) & 7) << 3) + (col & 7);
}

// ---------------- merged weight convert: W_in -> bf16, W_out*gnorm_w -> bf16 ----------
__global__ __launch_bounds__(256) void convert_weights_kernel(const float* __restrict__ W_in,
                                                              const float* __restrict__ W_out,
                                                              const float* __restrict__ gw,
                                                              short* __restrict__ winb,
                                                              short* __restrict__ woutb) {
    const int i = blockIdx.x * 256 + threadIdx.x;
    if (i < ZSTR * DMODEL)    winb[i]  = f2bf(W_in[i]);
    if (i < DMODEL * DINNER)  woutb[i] = f2bf(W_out[i] * gw[i % DINNER]);
}

// ---------------- rmsnorm of x (D=256) -> bf16 xn AND exact fp32 dt (8 heads) ----------
__global__ __launch_bounds__(256) void rmsnorm_dt_kernel(const float* __restrict__ x,
                                                         const float* __restrict__ w,
                                                         const float* __restrict__ W_in,
                                                         short* __restrict__ xn,
                                                         float* __restrict__ dt) {
    const int row  = blockIdx.x * 4 + (threadIdx.x >> 6);
    const int lane = threadIdx.x & 63;
    const float4 v = *(const float4*)(x + (size_t)row * DMODEL + lane * 4);
    float ss = v.x * v.x + v.y * v.y + v.z * v.z + v.w * v.w;
#pragma unroll
    for (int off = 1; off < 64; off <<= 1) ss += __shfl_xor(ss, off);
    const float rs = rsqrtf(ss * (1.0f / DMODEL) + 1.1920929e-7f);
    const float4 wv = *(const float4*)(w + lane * 4);
    const float4 xn4 = make_float4(v.x * rs * wv.x, v.y * rs * wv.y,
                                   v.z * rs * wv.z, v.w * rs * wv.w);
    short4 o;
    o.x = f2bf(xn4.x); o.y = f2bf(xn4.y); o.z = f2bf(xn4.z); o.w = f2bf(xn4.w);
    *(short4*)(xn + (size_t)row * DMODEL + lane * 4) = o;
#pragma unroll
    for (int h = 0; h < NHEADS; ++h) {
        const float4 ww = *(const float4*)(W_in + (size_t)(DPROJ - NHEADS + h) * DMODEL + lane * 4);
        float p = xn4.x * ww.x + xn4.y * ww.y + xn4.z * ww.z + xn4.w * ww.w;
#pragma unroll
        for (int off = 1; off < 64; off <<= 1) p += __shfl_xor(p, off);
        if (lane == 0) dt[(size_t)row * NHEADS + h] = p;
    }
}

// ---------------- bf16 MFMA GEMM: C[M][N] = A[M][K] * B[N][K]^T ----------
template <bool RES, typename OUT>
__global__ __launch_bounds__(256) void gemm_bf16_nt(const short* __restrict__ A,
                                                    const short* __restrict__ B,
                                                    const float* __restrict__ R,
                                                    const float* __restrict__ RS,
                                                    OUT* __restrict__ C,
                                                    int NX, int M, int N, int K, int LDA) {
    const int L   = blockIdx.x;
    const int xcd = L & 7;
    const int r   = L >> 3;
    const int mstrips_per_xcd = (M / 128) >> 3;
    const int mblk = xcd * mstrips_per_xcd + r / NX;
    const int nblk = r % NX;
    const int m0 = mblk * 128, n0 = nblk * 128;

    __shared__ __align__(16) short Asl[128 * 64];   // 16 KB
    __shared__ __align__(16) short Bsl[128 * 64];   // 16 KB
    const int tid  = threadIdx.x;
    const int lane = tid & 63;
    const int wid  = tid >> 6;
    const int wrow = (wid >> 1) * 64, wcol = (wid & 1) * 64;

    f32x4 acc[4][4];
#pragma unroll
    for (int m = 0; m < 4; ++m)
#pragma unroll
        for (int n = 0; n < 4; ++n) acc[m][n] = (f32x4)0.f;

    const int wbase = (tid & 0xC0) * 8;

    for (int k0 = 0; k0 < K; k0 += 64) {
#pragma unroll
        for (int rr = 0; rr < 4; ++rr) {
            const int idx = rr * 256 + tid;
            const int row = idx >> 3;
            const int cs  = idx & 7;
            const int ko  = (cs ^ (row & 7)) * 8;
            const int r6  = row & 63;
            const int brow = (row & 64) + (((r6 & 15) << 2) | (r6 >> 4));
            stage16(A + (size_t)(m0 + row) * LDA + k0 + ko, Asl + rr * 2048 + wbase);
            stage16(B + (size_t)(n0 + brow) * K + k0 + ko, Bsl + rr * 2048 + wbase);
        }
        __syncthreads();
#pragma unroll
        for (int ks = 0; ks < 2; ++ks) {
            bf16x8 af[4], bfr[4];
#pragma unroll
            for (int m = 0; m < 4; ++m) {
                const int arow = wrow + m * 16 + (lane & 15);
                const int ch = (ks * 4 + (lane >> 4)) ^ (arow & 7);
                af[m] = *(const bf16x8*)(Asl + arow * 64 + ch * 8);
            }
#pragma unroll
            for (int n = 0; n < 4; ++n) {
                const int brw = wcol + n * 16 + (lane & 15);
                const int ch = (ks * 4 + (lane >> 4)) ^ (brw & 7);
                bfr[n] = *(const bf16x8*)(Bsl + brw * 64 + ch * 8);
            }
#pragma unroll
            for (int m = 0; m < 4; ++m)
#pragma unroll
                for (int n = 0; n < 4; ++n)
                    acc[m][n] = __builtin_amdgcn_mfma_f32_16x16x32_bf16(af[m], bfr[n], acc[m][n], 0, 0, 0);
        }
        __syncthreads();
    }

    const int r0 = (lane >> 4) * 4;
    const int gcol = n0 + wcol + (lane & 15) * 4;
#pragma unroll
    for (int m = 0; m < 4; ++m) {
        const int grow = m0 + wrow + m * 16 + r0;
        if (gcol < N) {
#pragma unroll
            for (int reg = 0; reg < 4; ++reg) {
                if constexpr (sizeof(OUT) == 2) {
                    short4 o;
                    o.x = f2bf(acc[m][0][reg]); o.y = f2bf(acc[m][1][reg]);
                    o.z = f2bf(acc[m][2][reg]); o.w = f2bf(acc[m][3][reg]);
                    *(short4*)(C + (size_t)(grow + reg) * N + gcol) = o;
                } else {
                    f32x4 v;
                    v[0] = acc[m][0][reg]; v[1] = acc[m][1][reg];
                    v[2] = acc[m][2][reg]; v[3] = acc[m][3][reg];
                    if (RES) {
                        const float* rp = RS + (size_t)(grow + reg) * NHEADS;
                        const f32x4 s0 = *(const f32x4*)rp;
                        const f32x4 s1 = *(const f32x4*)(rp + 4);
                        const float sum = s0[0] + s0[1] + s0[2] + s0[3] +
                                          s1[0] + s1[1] + s1[2] + s1[3];
                        const float rsn = __builtin_amdgcn_rsqf(sum * (1.0f / DINNER) + 1e-5f);
                        v *= rsn;
                        v += *(const f32x4*)(R + (size_t)(grow + reg) * N + gcol);
                    }
                    *(f32x4*)(C + (size_t)(grow + reg) * N + gcol) = v;
                }
            }
        }
    }
}

// ---- depthwise causal conv(4) + bias + SiLU: sliding window, 8 rows x 8 ch per thread ----
__global__ __launch_bounds__(256) void conv_silu_kernel(const short* __restrict__ zxb,
                                                        const float* __restrict__ cw,
                                                        const float* __restrict__ cb,
                                                        short* __restrict__ xbc) {
    const int idx = blockIdx.x * 256 + threadIdx.x;   // over (NROWS/8)*80
    const int c8  = (idx % 80) * 8;
    const int bl0 = (idx / 80) * 8;                   // first of 8 rows
    const int l0  = bl0 & (SEQ - 1);
    const short* src = zxb + (size_t)bl0 * ZSTR + DINNER + c8;

    float4 w4[8];
    float bias[8];
#pragma unroll
    for (int j = 0; j < 8; ++j) w4[j] = *(const float4*)(cw + (c8 + j) * 4);
    {
        const float4 b0 = *(const float4*)(cb + c8);
        const float4 b1 = *(const float4*)(cb + c8 + 4);
        bias[0] = b0.x; bias[1] = b0.y; bias[2] = b0.z; bias[3] = b0.w;
        bias[4] = b1.x; bias[5] = b1.y; bias[6] = b1.z; bias[7] = b1.w;
    }

    bf16x8 rowv[11];                                  // rows l0-3 .. l0+7
#pragma unroll
    for (int m = 0; m < 11; ++m) {
        if (l0 + m - 3 >= 0)
            rowv[m] = *(const bf16x8*)(src + (ptrdiff_t)(m - 3) * ZSTR);
        else
            rowv[m] = (bf16x8)0;
    }

#pragma unroll
    for (int r = 0; r < 8; ++r) {
        float acc[8];
#pragma unroll
        for (int j = 0; j < 8; ++j) acc[j] = bias[j];
#pragma unroll
        for (int k = 0; k < 4; ++k) {
            const bf16x8 tap = rowv[r + k];
#pragma unroll
            for (int j = 0; j < 8; ++j)
                acc[j] = fmaf(bf2f(tap[j]), ((const float*)&w4[j])[k], acc[j]);
        }
        short8v o;
#pragma unroll
        for (int j = 0; j < 8; ++j)
            o[j] = f2bf(silu_fast(acc[j]));
        *(short8v*)(xbc + (size_t)(bl0 + r) * CONVDIM + c8) = o;
    }
}

// ---------------- scan pass 1 (MFMA): L[p][n] = sum_t X[t][p] * (w_t * B[t][n]) ----------
__global__ __launch_bounds__(256) void chunk_state_mfma(const float* __restrict__ dt,
                                                        const short* __restrict__ xbc,
                                                        const float* __restrict__ dt_bias,
                                                        const float* __restrict__ A_log,
                                                        short* __restrict__ lstate,
                                                        float* __restrict__ decayC) {
    const int bhc = blockIdx.x;
    const int c = bhc & (NCHUNK - 1), bh = bhc >> 6, h = bh & (NHEADS - 1), b = bh >> 3;
    const int tid = threadIdx.x, lane = tid & 63, wid = tid >> 6;
    __shared__ short XT[64 * LSTR];   // X^T, slot-permuted
    __shared__ short BT[64 * LSTR];   // (w*B)^T, slot-permuted
    const size_t row0 = (size_t)b * SEQ + (size_t)c * CHUNK;

    const float aneg  = -__expf(A_log[h]);
    const float dbias = dt_bias[h];
    const float draw = dt[(row0 + lane) * NHEADS + h] + dbias;
    const float dtv  = (draw > 20.f) ? draw : log1pf(__expf(draw));
    float cum = aneg * dtv;
#pragma unroll
    for (int off = 1; off < 64; off <<= 1) {
        const float nv = __shfl_up(cum, off);
        if (lane >= off) cum += nv;
    }
    const float total = __shfl(cum, 63);
    const float wval  = __expf(total - cum) * dtv;
    if (tid == 63) decayC[bhc] = __expf(total);

#pragma unroll
    for (int r = 0; r < 4; ++r) {
        const int idx  = tid + r * 256;
        const int trow = idx >> 4;
        const int q    = idx & 15;
        const int c4   = q * 4;
        const short* rp = xbc + (row0 + trow) * CONVDIM;
        const short4 xv = *(const short4*)(rp + h * 64 + c4);
        const short4 bv = *(const short4*)(rp + DINNER + c4);
        const float w = __shfl(wval, trow);
        XT[(0 * 16 + q) * LSTR + trow] = xv.x;
        XT[(1 * 16 + q) * LSTR + trow] = xv.y;
        XT[(2 * 16 + q) * LSTR + trow] = xv.z;
        XT[(3 * 16 + q) * LSTR + trow] = xv.w;
        BT[(0 * 16 + q) * LSTR + trow] = f2bf(bf2f(bv.x) * w);
        BT[(1 * 16 + q) * LSTR + trow] = f2bf(bf2f(bv.y) * w);
        BT[(2 * 16 + q) * LSTR + trow] = f2bf(bf2f(bv.z) * w);
        BT[(3 * 16 + q) * LSTR + trow] = f2bf(bf2f(bv.w) * w);
    }
    __syncthreads();

    f32x4 acc[4];
#pragma unroll
    for (int n = 0; n < 4; ++n) acc[n] = (f32x4)0.f;
#pragma unroll
    for (int ks = 0; ks < 2; ++ks) {
        const bf16x8 af = *(const bf16x8*)(XT + (wid * 16 + (lane & 15)) * LSTR + ks * 32 + (lane >> 4) * 8);
#pragma unroll
        for (int n = 0; n < 4; ++n) {
            const bf16x8 bfv = *(const bf16x8*)(BT + (n * 16 + (lane & 15)) * LSTR + ks * 32 + (lane >> 4) * 8);
            acc[n] = __builtin_amdgcn_mfma_f32_16x16x32_bf16(af, bfv, acc[n], 0, 0, 0);
        }
    }
    short* lp = lstate + ((size_t)bhc << 12);
    const int hi = lane >> 4;
    const int ncol = (lane & 15) * 4;
#pragma unroll
    for (int reg = 0; reg < 4; ++reg) {
        const int p = 16 * hi + 4 * reg + wid;
        short4 o;
        o.x = f2bf(acc[0][reg]); o.y = f2bf(acc[1][reg]);
        o.z = f2bf(acc[2][reg]); o.w = f2bf(acc[3][reg]);
        *(short4*)(lp + p * 64 + ncol) = o;
    }
}

// ---------------- scan pass 2: inter-chunk recurrence, short4-wide ----------
__global__ __launch_bounds__(256) void state_prefix_kernel(short* __restrict__ lstate,
                                                           const float* __restrict__ decayC) {
    const int idx = blockIdx.x * 256 + threadIdx.x;
    const int bh  = idx >> 10;
    const int pn4 = (idx & 1023) * 4;
    float S0 = 0.f, S1 = 0.f, S2 = 0.f, S3 = 0.f;
    for (int c = 0; c < NCHUNK; ++c) {
        short4* ptr = (short4*)(lstate + (((size_t)bh * NCHUNK + c) << 12) + pn4);
        const short4 l4 = *ptr;
        short4 o;
        o.x = f2bf(S0); o.y = f2bf(S1); o.z = f2bf(S2); o.w = f2bf(S3);
        *ptr = o;
        const float d = decayC[bh * NCHUNK + c];
        S0 = fmaf(S0, d, bf2f(l4.x));
        S1 = fmaf(S1, d, bf2f(l4.y));
        S2 = fmaf(S2, d, bf2f(l4.z));
        S3 = fmaf(S3, d, bf2f(l4.w));
    }
}

// ---- scan pass 3 (MFMA): y = mask(C@B^T)@X + exp(cum)*(C@SP^T) + Dp*X, fused gating.
// Mask decay: adaptive factored exp. Shift by chunk max cum0: E_s = exp(cum_s-cum0)<=1,
// D_t = dt*exp(cum0-cum_t) <= dt*e^range — safe iff range < 80 (wave-uniform branch);
// else exact per-entry exp (r18 path). ----
__global__ __launch_bounds__(256) void chunk_scan_mfma(const float* __restrict__ dt,
                                                       short* __restrict__ xbc,
                                                       const short* __restrict__ zxb,
                                                       float* __restrict__ rowss,
                                                       const float* __restrict__ dt_bias,
                                                       const float* __restrict__ A_log,
                                                       const float* __restrict__ Dp,
                                                       const short* __restrict__ lstate) {
    const int bhc = blockIdx.x;
    const int c = bhc & (NCHUNK - 1), bh = bhc >> 6, h = bh & (NHEADS - 1), b = bh >> 3;
    const int tid = threadIdx.x, lane = tid & 63, wid = tid >> 6;
    __shared__ short BsMs[64 * 64]; // B rows [t][n]; later masked scores [s][t]
    __shared__ short Cs[64 * 64];   // C rows [s][n]
    __shared__ short XT[64 * 64];   // X^T, slot-permuted
    __shared__ short SP[64 * 64];   // prefix state, slot-permuted
    short* Bs = BsMs;
    short* Ms = BsMs;
    const size_t row0 = (size_t)b * SEQ + (size_t)c * CHUNK;

    // per-wave redundant fp32 prefix of aneg*dt (identical across waves)
    const float aneg  = -__expf(A_log[h]);
    const float dbias = dt_bias[h];
    const float draw = dt[(row0 + lane) * NHEADS + h] + dbias;
    const float dtv  = (draw > 20.f) ? draw : log1pf(__expf(draw));
    float cum = aneg * dtv;
#pragma unroll
    for (int off = 1; off < 64; off <<= 1) {
        const float nv = __shfl_up(cum, off);
        if (lane >= off) cum += nv;
    }
    const float cum0  = __shfl(cum, 0);                 // chunk max (cum decreasing)
    const float range = cum0 - __shfl(cum, 63);         // >= 0
    const bool  fast  = (range < 80.f);                 // wave-uniform
    float Efac = 0.f, Dfac = 0.f;
    if (fast) {
        Efac = __expf(cum - cum0);                      // <= 1, > e^-80 (no underflow)
        Dfac = dtv * __expf(cum0 - cum);                // <= dt * e^80 (finite)
    }

#pragma unroll
    for (int r = 0; r < 4; ++r) {
        const int idx  = tid + r * 256;
        const int trow = idx >> 4;
        const int q    = idx & 15;
        const int c4   = q * 4;
        const short* rp = xbc + (row0 + trow) * CONVDIM;
        const short4 xv = *(const short4*)(rp + h * 64 + c4);
        const int hoff = ((((q >> 1) ^ trow) & 7) << 3) + (q & 1) * 4;
        *(short4*)(Bs + trow * 64 + hoff) = *(const short4*)(rp + DINNER + c4);
        *(short4*)(Cs + trow * 64 + hoff) = *(const short4*)(rp + DINNER + DSTATE + c4);
        XT[swz(0 * 16 + q, trow)] = xv.x;
        XT[swz(1 * 16 + q, trow)] = xv.y;
        XT[swz(2 * 16 + q, trow)] = xv.z;
        XT[swz(3 * 16 + q, trow)] = xv.w;
    }
#pragma unroll
    for (int r = 0; r < 4; ++r) {
        const int idx = tid + r * 256;
        const int p = idx >> 4, q = idx & 15;
        const int pslot = ((p & 3) << 4) | (p >> 2);
        const int hoff = ((((q >> 1) ^ pslot) & 7) << 3) + (q & 1) * 4;
        *(short4*)(SP + pslot * 64 + hoff) =
            *(const short4*)(lstate + ((size_t)bhc << 12) + p * 64 + q * 4);
    }
    __syncthreads();

    // G = C @ B^T (over n)
    f32x4 accG[4];
#pragma unroll
    for (int tf = 0; tf < 4; ++tf) accG[tf] = (f32x4)0.f;
    __builtin_amdgcn_s_setprio(1);
#pragma unroll
    for (int ks = 0; ks < 2; ++ks) {
        const int crow = wid * 16 + (lane & 15);
        const bf16x8 af = *(const bf16x8*)(Cs + crow * 64 + (((ks * 4 + (lane >> 4)) ^ crow) & 7) * 8);
#pragma unroll
        for (int tf = 0; tf < 4; ++tf) {
            const int brw = tf * 16 + (lane & 15);
            const bf16x8 bfv = *(const bf16x8*)(Bs + brw * 64 + (((ks * 4 + (lane >> 4)) ^ brw) & 7) * 8);
            accG[tf] = __builtin_amdgcn_mfma_f32_16x16x32_bf16(af, bfv, accG[tf], 0, 0, 0);
        }
    }
    __builtin_amdgcn_s_setprio(0);
    __syncthreads();   // all waves done reading Bs before Ms overlays it

    // causal mask + decay scale -> Ms (bf16), overlaid on Bs
    const int srow0 = wid * 16 + (lane >> 4) * 4;
    float csr[4];
#pragma unroll
    for (int reg = 0; reg < 4; ++reg) csr[reg] = __shfl(cum, srow0 + reg);
    if (fast) {
        float esh[4];
#pragma unroll
        for (int reg = 0; reg < 4; ++reg) esh[reg] = __shfl(Efac, srow0 + reg);
#pragma unroll
        for (int tf = 0; tf < 4; ++tf) {
            const int t = tf * 16 + (lane & 15);
            const float Dt = __shfl(Dfac, t);
#pragma unroll
            for (int reg = 0; reg < 4; ++reg) {
                const int s = srow0 + reg;
                const float m = (t <= s) ? accG[tf][reg] * esh[reg] * Dt : 0.f;
                Ms[swz(s, t)] = f2bf(m);
            }
        }
    } else {
#pragma unroll
        for (int tf = 0; tf < 4; ++tf) {
            const int t = tf * 16 + (lane & 15);
            const float ct  = __shfl(cum, t);
            const float dtt = __shfl(dtv, t);
#pragma unroll
            for (int reg = 0; reg < 4; ++reg) {
                const int s = srow0 + reg;
                const float m = (t <= s) ? accG[tf][reg] * __expf(csr[reg] - ct) * dtt : 0.f;
                Ms[swz(s, t)] = f2bf(m);
            }
        }
    }
    __syncthreads();

    // Y1 = M @ X ; Y2 = C @ SP^T
    f32x4 acc1[4], acc2[4];
#pragma unroll
    for (int pf = 0; pf < 4; ++pf) { acc1[pf] = (f32x4)0.f; acc2[pf] = (f32x4)0.f; }
    __builtin_amdgcn_s_setprio(1);
#pragma unroll
    for (int ks = 0; ks < 2; ++ks) {
        const int mrow = wid * 16 + (lane & 15);
        const int ch = ks * 4 + (lane >> 4);
        const bf16x8 am = *(const bf16x8*)(Ms + mrow * 64 + ((ch ^ mrow) & 7) * 8);
        const bf16x8 ac = *(const bf16x8*)(Cs + mrow * 64 + ((ch ^ mrow) & 7) * 8);
#pragma unroll
        for (int pf = 0; pf < 4; ++pf) {
            const int prow = pf * 16 + (lane & 15);
            const bf16x8 bx = *(const bf16x8*)(XT + prow * 64 + ((ch ^ prow) & 7) * 8);
            const bf16x8 bs = *(const bf16x8*)(SP + prow * 64 + ((ch ^ prow) & 7) * 8);
            acc1[pf] = __builtin_amdgcn_mfma_f32_16x16x32_bf16(am, bx, acc1[pf], 0, 0, 0);
            acc2[pf] = __builtin_amdgcn_mfma_f32_16x16x32_bf16(ac, bs, acc2[pf], 0, 0, 0);
        }
    }
    __builtin_amdgcn_s_setprio(0);
    const float dpv = Dp[h];
    float es[4];
#pragma unroll
    for (int reg = 0; reg < 4; ++reg) es[reg] = __expf(csr[reg]);
    const int j = lane & 15;
#pragma unroll
    for (int reg = 0; reg < 4; ++reg) {
        const int s = srow0 + reg;
        const short4 z4 = *(const short4*)(zxb + (row0 + s) * ZSTR + h * 64 + j * 4);
        short4 o;
        float ssq = 0.f;
#pragma unroll
        for (int pf = 0; pf < 4; ++pf) {
            const float xv = bf2f(XT[swz(pf * 16 + j, s)]);
            const float yv = acc1[pf][reg] + es[reg] * acc2[pf][reg] + dpv * xv;
            const float v  = yv * silu_fast(bf2f(((const short*)&z4)[pf]));
            ((short*)&o)[pf] = f2bf(v);
            ssq = fmaf(v, v, ssq);
        }
        *(short4*)(xbc + (row0 + s) * CONVDIM + h * 64 + j * 4) = o;
        ssq += __shfl_xor(ssq, 1);
        ssq += __shfl_xor(ssq, 2);
        ssq += __shfl_xor(ssq, 4);
        ssq += __shfl_xor(ssq, 8);
        if (j == 0) rowss[(row0 + s) * NHEADS + h] = ssq;
    }
}

// ---------------- launch ----------------
extern "C" void kernel_launch(void* const* d_in, const int* in_sizes, int n_in,
                              void* d_out, int out_size, void* d_ws, size_t ws_size,
                              hipStream_t stream) {
    (void)in_sizes; (void)n_in; (void)out_size; (void)d_ws; (void)ws_size;
    const float* x      = (const float*)d_in[0];
    const float* W_in   = (const float*)d_in[1];
    const float* conv_w = (const float*)d_in[2];
    const float* conv_b = (const float*)d_in[3];
    const float* dt_b   = (const float*)d_in[4];
    const float* A_log  = (const float*)d_in[5];
    const float* Dp     = (const float*)d_in[6];
    const float* g_w    = (const float*)d_in[7];
    const float* n_w    = (const float*)d_in[8];
    const float* W_out  = (const float*)d_in[9];
    float* out = (float*)d_out;

    short *xn, *zxb, *xbc, *winb, *woutb, *lst;
    float *dtv, *dcy, *rss;
    hipGetSymbolAddress((void**)&xn,    HIP_SYMBOL(g_xn));
    hipGetSymbolAddress((void**)&zxb,   HIP_SYMBOL(g_zxb));
    hipGetSymbolAddress((void**)&xbc,   HIP_SYMBOL(g_xbc));
    hipGetSymbolAddress((void**)&dtv,   HIP_SYMBOL(g_dt));
    hipGetSymbolAddress((void**)&rss,   HIP_SYMBOL(g_rowss));
    hipGetSymbolAddress((void**)&lst,   HIP_SYMBOL(g_lstate));
    hipGetSymbolAddress((void**)&dcy,   HIP_SYMBOL(g_decayC));
    hipGetSymbolAddress((void**)&winb,  HIP_SYMBOL(g_Winb));
    hipGetSymbolAddress((void**)&woutb, HIP_SYMBOL(g_Woutb));

    convert_weights_kernel<<<(ZSTR * DMODEL) / 256, 256, 0, stream>>>(
        W_in, W_out, g_w, winb, woutb);

    rmsnorm_dt_kernel<<<NROWS / 4, 256, 0, stream>>>(x, n_w, W_in, xn, dtv);

    gemm_bf16_nt<false, short><<<(ZSTR / 128) * (NROWS / 128), 256, 0, stream>>>(
        xn, winb, nullptr, nullptr, zxb, ZSTR / 128, NROWS, ZSTR, DMODEL, DMODEL);

    conv_silu_kernel<<<(NROWS / 8 * 80) / 256, 256, 0, stream>>>(zxb, conv_w, conv_b, xbc);

    chunk_state_mfma<<<BATCH * NHEADS * NCHUNK, 256, 0, stream>>>(dtv, xbc, dt_b, A_log, lst, dcy);
    state_prefix_kernel<<<(BATCH * NHEADS * HEADDIM * DSTATE) / (4 * 256), 256, 0, stream>>>(lst, dcy);
    chunk_scan_mfma<<<BATCH * NHEADS * NCHUNK, 256, 0, stream>>>(
        dtv, xbc, zxb, rss, dt_b, A_log, Dp, lst);

    gemm_bf16_nt<true, float><<<(DMODEL / 128) * (NROWS / 128), 256, 0, stream>>>(
        xbc, woutb, x, rss, out, DMODEL / 128, NROWS, DMODEL, DINNER, CONVDIM);
}